// Round 1
// baseline (401.839 us; speedup 1.0000x reference)
//
#include <hip/hip_runtime.h>

typedef unsigned short u16;
typedef unsigned int u32;
typedef __attribute__((ext_vector_type(4))) float f32x4;
typedef __attribute__((ext_vector_type(8))) short s16x8;
typedef __attribute__((ext_vector_type(4))) unsigned int u32x4;

#define DEVI static __device__ __forceinline__

// B=2, S=2048, E=2048, H=16, D=128, MP=4, local=512; qkv cols: [q(512) v(512) k(512)] x4
// k-rope fused into QKV-GEMM epilogue; q-rope (+ (1/sqrt(128))*log2(e) scale) fused into
// attention prologue; softmax in exp2 domain.

#define ROPE_C (-13.287712379549449f / 32.0f)  // -log2(10000)/32
#define QSCALE 0.12751743f                     // log2(e)/sqrt(128)

DEVI u16 f2bf(float f) {
  u32 u = __float_as_uint(f);
  return (u16)((u + 0x7FFFu + ((u >> 16) & 1u)) >> 16);  // round-to-nearest-even
}
DEVI float bf2f(u16 h) { return __uint_as_float(((u32)h) << 16); }

DEVI void async_copy16(const u16* g, u16* l) {
  // dest = wave-uniform LDS base + lane*16 (gfx950 global_load_lds_dwordx4)
  __builtin_amdgcn_global_load_lds((__attribute__((address_space(1))) void*)g,
                                   (__attribute__((address_space(3))) void*)l, 16, 0, 0);
}

// fused fp32->bf16 cast of all three inputs
__global__ __launch_bounds__(256) void cast3_kernel(
    const float* __restrict__ s0, u16* __restrict__ d0, int n0,
    const float* __restrict__ s1, u16* __restrict__ d1, int n1,
    const float* __restrict__ s2, u16* __restrict__ d2, int n2) {
  int i = blockIdx.x * 256 + threadIdx.x;
  const float* s;
  u16* d;
  if (i < n0) {
    s = s0; d = d0;
  } else if (i < n0 + n1) {
    s = s1; d = d1; i -= n0;
  } else if (i < n0 + n1 + n2) {
    s = s2; d = d2; i -= n0 + n1;
  } else {
    return;
  }
  const float4 v = ((const float4*)s)[i];
  ushort4 o;
  o.x = f2bf(v.x); o.y = f2bf(v.y); o.z = f2bf(v.z); o.w = f2bf(v.w);
  ((ushort4*)d)[i] = o;
}

// C[m,n] = sum_k A[m,k]*B[n,k]; A,B row-major bf16, K contiguous (B^T GEMM).
// 128x128 tile, BK=32, 4 waves 2x2 of 64x64, 16x16x32 MFMA, 4x4 frags/wave.
// R4 structure: A,B staged through 3-deep LDS via global_load_lds w16, XOR-swizzled,
// vmcnt(4) + raw s_barrier in steady state. Used for the output projection (EPI=0).
template <int EPI>
__global__ __launch_bounds__(256, 3) void gemm_bt_kernel(
    const u16* __restrict__ A, const u16* __restrict__ Bm, int K, int N,
    float* __restrict__ C, u16* __restrict__ qo, u16* __restrict__ ko, u16* __restrict__ vo) {
  __shared__ __attribute__((aligned(16))) u16 As[3][128 * 32];  // 8KB each
  __shared__ __attribute__((aligned(16))) u16 Bs[3][128 * 32];  // 8KB each
  const int tid = threadIdx.x;
  const int w = tid >> 6, lane = tid & 63;
  const int quad = lane >> 4, l16 = lane & 15;
  const int wrow = (w >> 1) * 64, wcol = (w & 1) * 64;
  const long tileM = (long)blockIdx.y * 128;
  const long tileN = (long)blockIdx.x * 128;

  f32x4 acc[4][4];
#pragma unroll
  for (int i = 0; i < 4; ++i)
#pragma unroll
    for (int j = 0; j < 4; ++j) acc[i][j] = f32x4{0.f, 0.f, 0.f, 0.f};

  // staging: wave w covers tile rows [w*32, w*32+32) in two 16-row chunks.
  const u16* aptr[2];
  const u16* bptr[2];
  int ldso[2];
#pragma unroll
  for (int c = 0; c < 2; ++c) {
    const int r0 = (w * 2 + c) * 16;
    const int row = r0 + (lane >> 2);
    const int colsw = (((lane & 3) ^ ((row >> 1) & 3)) << 3);
    aptr[c] = A + (tileM + row) * (long)K + colsw;
    bptr[c] = Bm + (tileN + row) * (long)K + colsw;
    ldso[c] = r0 * 32;
  }

  auto stage = [&](int k0, int buf) {
#pragma unroll
    for (int c = 0; c < 2; ++c) {
      async_copy16(aptr[c] + k0, &As[buf][ldso[c]]);
      async_copy16(bptr[c] + k0, &Bs[buf][ldso[c]]);
    }
  };

  stage(0, 0);
  stage(32, 1);

  const int psw = (quad ^ ((l16 >> 1) & 3)) << 3;  // read-side swizzle (lane-constant)

  int bt = 0;
  for (int k0 = 0; k0 < K; k0 += 32) {
    if (k0 + 32 < K)
      __builtin_amdgcn_s_waitcnt(0x0f74);  // vmcnt(4): tile t landed, t+1 in flight
    else
      __builtin_amdgcn_s_waitcnt(0x0f70);  // last tile: vmcnt(0)
    __builtin_amdgcn_s_barrier();          // raw barrier: no compiler-forced drain
    if (k0 + 64 < K) stage(k0 + 64, bt == 0 ? 2 : bt - 1);

    s16x8 af[4], bfr[4];
#pragma unroll
    for (int i = 0; i < 4; ++i)
      af[i] = *(const s16x8*)(&As[bt][(wrow + i * 16 + l16) * 32 + psw]);
#pragma unroll
    for (int j = 0; j < 4; ++j)
      bfr[j] = *(const s16x8*)(&Bs[bt][(wcol + j * 16 + l16) * 32 + psw]);
#pragma unroll
    for (int i = 0; i < 4; ++i)
#pragma unroll
      for (int j = 0; j < 4; ++j)
        acc[i][j] = __builtin_amdgcn_mfma_f32_16x16x32_bf16(af[i], bfr[j], acc[i][j], 0, 0, 0);
    bt = bt == 2 ? 0 : bt + 1;
  }

  // ---- inline epilogue ----
  const int b = (int)(tileM >> 11);
#pragma unroll
  for (int i = 0; i < 4; ++i) {
#pragma unroll
    for (int j = 0; j < 4; ++j) {
      const int rowb = (int)((tileM + wrow + i * 16 + quad * 4) & 2047);
      if (EPI == 0) {
#pragma unroll
        for (int r = 0; r < 4; ++r) {
          const long row = tileM + wrow + i * 16 + quad * 4 + r;
          C[row * N + tileN + wcol + j * 16 + l16] = acc[i][j][r];
        }
      } else {
        const long col0 = tileN + wcol + j * 16;
        const int mp = (int)(col0 / 1536);
        const int cc0 = (int)(col0 - (long)mp * 1536);
        const int part = cc0 >> 9;
        const int idx0 = cc0 & 511;
        const int head = mp * 4 + (idx0 >> 7);
        const int dim0 = idx0 & 127;
        const int dim = dim0 + l16;
        const long bh = (long)(b * 16 + head);
        if (part == 1) {
#pragma unroll
          for (int r = 0; r < 4; ++r)
            vo[(bh * 128 + dim) * 2048 + rowb + r] = f2bf(acc[i][j][r]);
        } else {
          float y[4];
          if (part == 2 && dim0 < 64) {
            const int jj = dim >> 1;
            const float inv = exp2f((float)jj * ROPE_C);
#pragma unroll
            for (int r = 0; r < 4; ++r) {
              const float v = acc[i][j][r];
              const float pv = __shfl_xor(v, 1, 64);
              const float ang = (float)(rowb + r) * inv;
              const float sn = __sinf(ang), cs = __cosf(ang);
              y[r] = (l16 & 1) ? (v * cs + pv * sn) : (v * cs - pv * sn);
            }
          } else {
#pragma unroll
            for (int r = 0; r < 4; ++r) y[r] = acc[i][j][r];
          }
          u16* dst = (part == 0) ? qo : ko;
#pragma unroll
          for (int r = 0; r < 4; ++r)
            dst[(bh * 2048 + rowb + r) * 128 + dim] = f2bf(y[r]);
        }
      }
    }
  }
}

// QKV projection: 256x256 tile, BK=64, 8 waves (2M x 4N, 512 thr), 8-phase schedule.
// Per K-tile, 4 phases = C-quadrants Q(mh,nh):
//   ph1: read A-half(wm)[rows 0..63] (8 b128) + B[wn cols 0..31] (4) -> 16 MFMA Q00
//   ph2: read B[wn cols 32..63] (4)                               -> 16 MFMA Q01
//   ph3: stage B(t+2) [B slots free after ph2]; read A rows 64..127 -> 16 MFMA Q10
//   ph4: stage A(t+2) [A slots free after ph3]                     -> 16 MFMA Q11
//        vmcnt(8) (= this tile's 8 stage loads in flight; all of t+1 landed) + barrier.
// LDS = 2buf x 2half ring per operand (128 KiB total); granule-XOR swizzle both sides
// (linear DMA dest + inverse-swizzled global source + swizzled ds_read). setprio(1)
// around each MFMA cluster (T5). Accumulation order identical to gemm_bt_kernel.
// Fused epilogue: scatter q / k(roped) / v^T.
__global__ __launch_bounds__(512, 2) void gemm_qkv256_kernel(
    const u16* __restrict__ A, const u16* __restrict__ Bm, int K,
    u16* __restrict__ qo, u16* __restrict__ ko, u16* __restrict__ vo) {
  __shared__ __attribute__((aligned(16))) u16 As[2][2][128 * 64];  // 64KB
  __shared__ __attribute__((aligned(16))) u16 Bs[2][2][128 * 64];  // 64KB
  const int tid = threadIdx.x;
  const int w = tid >> 6, lane = tid & 63;
  const int quad = lane >> 4, l16 = lane & 15;
  const int wm = w >> 2, wn = w & 3;  // wave tile: rows [wm*128,+128), cols [wn*64,+64)
  const long tileM = (long)blockIdx.y * 256;
  const long tileN = (long)blockIdx.x * 256;

  f32x4 acc[8][4];
#pragma unroll
  for (int i = 0; i < 8; ++i)
#pragma unroll
    for (int j = 0; j < 4; ++j) acc[i][j] = f32x4{0.f, 0.f, 0.f, 0.f};

  // staging: per half-tile (128 rows), wave w covers rows [w*16, w*16+16) as 2 loads
  // of 8 rows; lane -> row w*16+c*8+(lane>>3), granule (lane&7)^(row&7) (inverse swz).
  const int rowoff = lane >> 3;                 // 0..7 == row&7 of the staged row
  const int swz = ((lane & 7) ^ rowoff) << 3;   // u16 offset within 64-col row
  const u16* aBase = A + (tileM + w * 16 + rowoff) * (long)K + swz;
  const u16* bBase = Bm + (tileN + w * 16 + rowoff) * (long)K + swz;
  const int ldsb = (w * 16) * 64;

  auto stageA2 = [&](int t) {  // both A halves of tile t: 4 loads
    const int buf = t & 1;
    const long k0 = (long)t << 6;
#pragma unroll
    for (int h = 0; h < 2; ++h)
#pragma unroll
      for (int c = 0; c < 2; ++c)
        async_copy16(aBase + (long)(h * 128 + c * 8) * K + k0,
                     &As[buf][h][ldsb + c * 8 * 64]);
  };
  auto stageB2 = [&](int t) {  // both B halves of tile t: 4 loads
    const int buf = t & 1;
    const long k0 = (long)t << 6;
#pragma unroll
    for (int h = 0; h < 2; ++h)
#pragma unroll
      for (int c = 0; c < 2; ++c)
        async_copy16(bBase + (long)(h * 128 + c * 8) * K + k0,
                     &Bs[buf][h][ldsb + c * 8 * 64]);
  };

  const int gsw = l16 & 7;  // read-side granule XOR (row&7 == l16&7 for frag rows)
  auto rdA = [&](int buf, int i, int kk) -> s16x8 {  // i: 0..7 local m-frag
    return *(const s16x8*)(
        &As[buf][wm][(i * 16 + l16) * 64 + ((((kk << 2) + quad) ^ gsw) << 3)]);
  };
  auto rdB = [&](int buf, int j, int kk) -> s16x8 {  // j: 0..3 local n-frag
    return *(const s16x8*)(
        &Bs[buf][wn >> 1][(((wn & 1) * 64) + j * 16 + l16) * 64 +
                          ((((kk << 2) + quad) ^ gsw) << 3)]);
  };

  const int NT = K >> 6;
  // prologue: tiles 0 and 1 (per-tile issue order B(4),A(4) matches main loop)
  stageB2(0); stageA2(0);
  stageB2(1); stageA2(1);
  __builtin_amdgcn_s_waitcnt(0x0f78);  // vmcnt(8): tile 0 landed, tile 1 in flight
  __builtin_amdgcn_s_barrier();

  for (int t = 0; t < NT; ++t) {
    const int buf = t & 1;
    const bool pf = (t + 2 < NT);
    s16x8 a[4][2], b0[2][2], b1[2][2];

    // ---- phase 1: A-half(local rows 0..63) + B cols 0..31 -> Q(0,0)
#pragma unroll
    for (int i = 0; i < 4; ++i)
#pragma unroll
      for (int kk = 0; kk < 2; ++kk) a[i][kk] = rdA(buf, i, kk);
#pragma unroll
    for (int j = 0; j < 2; ++j)
#pragma unroll
      for (int kk = 0; kk < 2; ++kk) b0[j][kk] = rdB(buf, j, kk);
    __builtin_amdgcn_s_barrier();
    __builtin_amdgcn_s_setprio(1);
#pragma unroll
    for (int i = 0; i < 4; ++i)
#pragma unroll
      for (int j = 0; j < 2; ++j)
#pragma unroll
        for (int kk = 0; kk < 2; ++kk)
          acc[i][j] =
              __builtin_amdgcn_mfma_f32_16x16x32_bf16(a[i][kk], b0[j][kk], acc[i][j], 0, 0, 0);
    __builtin_amdgcn_s_setprio(0);
    __builtin_amdgcn_s_barrier();

    // ---- phase 2: B cols 32..63 -> Q(0,1)
#pragma unroll
    for (int j = 0; j < 2; ++j)
#pragma unroll
      for (int kk = 0; kk < 2; ++kk) b1[j][kk] = rdB(buf, 2 + j, kk);
    __builtin_amdgcn_s_barrier();
    __builtin_amdgcn_s_setprio(1);
#pragma unroll
    for (int i = 0; i < 4; ++i)
#pragma unroll
      for (int j = 0; j < 2; ++j)
#pragma unroll
        for (int kk = 0; kk < 2; ++kk)
          acc[i][2 + j] = __builtin_amdgcn_mfma_f32_16x16x32_bf16(a[i][kk], b1[j][kk],
                                                                  acc[i][2 + j], 0, 0, 0);
    __builtin_amdgcn_s_setprio(0);
    __builtin_amdgcn_s_barrier();

    // ---- phase 3: stage B(t+2) [B slots of this buf fully read]; A rows 64..127 -> Q(1,0)
    if (pf) stageB2(t + 2);
#pragma unroll
    for (int i = 0; i < 4; ++i)
#pragma unroll
      for (int kk = 0; kk < 2; ++kk) a[i][kk] = rdA(buf, 4 + i, kk);
    __builtin_amdgcn_s_barrier();
    __builtin_amdgcn_s_setprio(1);
#pragma unroll
    for (int i = 0; i < 4; ++i)
#pragma unroll
      for (int j = 0; j < 2; ++j)
#pragma unroll
        for (int kk = 0; kk < 2; ++kk)
          acc[4 + i][j] = __builtin_amdgcn_mfma_f32_16x16x32_bf16(a[i][kk], b0[j][kk],
                                                                  acc[4 + i][j], 0, 0, 0);
    __builtin_amdgcn_s_setprio(0);
    __builtin_amdgcn_s_barrier();

    // ---- phase 4: stage A(t+2) [A slots fully read]; -> Q(1,1); counted vmcnt
    if (pf) stageA2(t + 2);
    __builtin_amdgcn_s_barrier();
    __builtin_amdgcn_s_setprio(1);
#pragma unroll
    for (int i = 0; i < 4; ++i)
#pragma unroll
      for (int j = 0; j < 2; ++j)
#pragma unroll
        for (int kk = 0; kk < 2; ++kk)
          acc[4 + i][2 + j] = __builtin_amdgcn_mfma_f32_16x16x32_bf16(
              a[i][kk], b1[j][kk], acc[4 + i][2 + j], 0, 0, 0);
    __builtin_amdgcn_s_setprio(0);
    if (pf)
      __builtin_amdgcn_s_waitcnt(0x0f78);  // vmcnt(8): only this tile's stages in flight
    else
      __builtin_amdgcn_s_waitcnt(0x0f70);  // tail: drain
    __builtin_amdgcn_s_barrier();
  }

  // ---- fused scatter epilogue (same mapping as gemm_bt_kernel<1>) ----
  const int b = (int)(tileM >> 11);  // 256-row tile never straddles batch
#pragma unroll
  for (int i = 0; i < 8; ++i) {
#pragma unroll
    for (int j = 0; j < 4; ++j) {
      const int rowb = (int)((tileM + wm * 128 + i * 16 + quad * 4) & 2047);
      const long col0 = tileN + wn * 64 + j * 16;  // wave-uniform base col of this frag
      const int mp = (int)(col0 / 1536);
      const int cc0 = (int)(col0 - (long)mp * 1536);
      const int part = cc0 >> 9;  // 0:q 1:v 2:k (uniform per frag)
      const int idx0 = cc0 & 511;
      const int head = mp * 4 + (idx0 >> 7);
      const int dim0 = idx0 & 127;
      const int dim = dim0 + l16;
      const long bh = (long)(b * 16 + head);
      if (part == 1) {
#pragma unroll
        for (int r = 0; r < 4; ++r)
          vo[(bh * 128 + dim) * 2048 + rowb + r] = f2bf(acc[i][j][r]);  // v^T
      } else {
        float y[4];
        if (part == 2 && dim0 < 64) {
          // k-rope: pair partner is adjacent lane (col parity == l16 parity)
          const int jj = dim >> 1;
          const float inv = exp2f((float)jj * ROPE_C);
#pragma unroll
          for (int r = 0; r < 4; ++r) {
            const float v = acc[i][j][r];
            const float pv = __shfl_xor(v, 1, 64);
            const float ang = (float)(rowb + r) * inv;
            const float sn = __sinf(ang), cs = __cosf(ang);
            y[r] = (l16 & 1) ? (v * cs + pv * sn) : (v * cs - pv * sn);
          }
        } else {
#pragma unroll
          for (int r = 0; r < 4; ++r) y[r] = acc[i][j][r];
        }
        u16* dst = (part == 0) ? qo : ko;
#pragma unroll
        for (int r = 0; r < 4; ++r)
          dst[(bh * 2048 + rowb + r) * 128 + dim] = f2bf(y[r]);
      }
    }
  }
}

// Flash attention v4: swapped-operand design. Block = 64 q rows (4 waves x 16 rows),
// 32-key LDS tiles (4 blocks/CU). S^T = K*Q^T (A=K, B=Q): each lane holds 8 scores of
// ONE q-row (keys in regs) -> softmax reduce = in-lane + 2 shfl; m/l scalars per lane;
// P enters PV as B-operand via an 8-shfl quad-exchange (no LDS round-trip);
// PV = V^T*P gives out^T whose stores vectorize as ushort4. Heavy-first grid.
__global__ __launch_bounds__(256, 4) void attn_kernel(
    const u16* __restrict__ q, const u16* __restrict__ k,
    const u16* __restrict__ vT, u16* __restrict__ out) {
  __shared__ __attribute__((aligned(16))) u16 Ks[2][32 * 128];  // 8KB each
  __shared__ __attribute__((aligned(16))) u16 Vs[2][128 * 32];  // 8KB each
  const int tid = threadIdx.x;
  const int w = tid >> 6, lane = tid & 63;
  const int quad = lane >> 4, l16 = lane & 15;
  const int qt = 31 - (blockIdx.x >> 5);  // heavy tiles dispatched first
  const int bh = blockIdx.x & 31;
  const int qbase = qt * 64 + w * 16;

  const u16* qp = q + ((long)bh * 2048 + qbase) * 128;
  const u16* kp = k + (long)bh * 2048 * 128;
  const u16* vp = vT + (long)bh * 128 * 2048;

  // Q B-frag: Q[n=l16][kdim = c*32 + quad*8 + j], roped + scaled in fp32
  const float spos = (float)(qbase + l16);
  s16x8 qf[4];
#pragma unroll
  for (int c = 0; c < 4; ++c) {
    const s16x8 raw = *(const s16x8*)(qp + l16 * 128 + c * 32 + quad * 8);
    s16x8 ov;
    if (c < 2) {  // dims < 64: rotate pairs (in-lane: 2m, 2m+1)
#pragma unroll
      for (int m = 0; m < 4; ++m) {
        const int jj = c * 16 + quad * 4 + m;
        const float inv = exp2f((float)jj * ROPE_C);
        const float ang = spos * inv;
        const float sn = __sinf(ang), cs = __cosf(ang);
        const float x0 = bf2f((u16)raw[2 * m]), x1 = bf2f((u16)raw[2 * m + 1]);
        ov[2 * m] = (short)f2bf((x0 * cs - x1 * sn) * QSCALE);
        ov[2 * m + 1] = (short)f2bf((x1 * cs + x0 * sn) * QSCALE);
      }
    } else {      // dims >= 64: pass-through, scale only
#pragma unroll
      for (int e = 0; e < 8; ++e) ov[e] = (short)f2bf(bf2f((u16)raw[e]) * QSCALE);
    }
    qf[c] = ov;
  }

  f32x4 acc[8];  // out^T: acc[dd] rows = dims dd*16+quad*4+r, col = q-row l16
#pragma unroll
  for (int d = 0; d < 8; ++d) acc[d] = f32x4{0.f, 0.f, 0.f, 0.f};
  float mrun = -1e30f, lrun = 0.f;  // per-lane scalars (q-row = qbase+l16)

  // stage one 32-key tile: wave w stages keys [w*8,w*8+8) and dims [w*32,w*32+32)
  auto stage = [&](int k0, int buf) {
    const int ko = lane >> 4, cl = lane & 15;
#pragma unroll
    for (int i = 0; i < 2; ++i) {
      const int keyt = w * 8 + i * 4;
      const int key = keyt + ko;
      async_copy16(kp + (long)(k0 + key) * 128 + ((cl ^ (key & 15)) << 3),
                   &Ks[buf][keyt * 128]);
    }
    const int ld = lane >> 2, c4 = lane & 3;
#pragma unroll
    for (int i = 0; i < 2; ++i) {
      const int db = w * 32 + i * 16;
      const int d = db + ld;
      async_copy16(vp + (long)d * 2048 + k0 + ((c4 ^ ((d >> 1) & 3)) << 3),
                   &Vs[buf][db * 32]);
    }
  };

  stage(0, 0);

  const int nt = 2 * qt + 2;
  for (int t = 0; t < nt; ++t) {
    const int k0 = t * 32;
    const u16* Ksc = Ks[t & 1];
    const u16* Vsc = Vs[t & 1];
    __builtin_amdgcn_s_waitcnt(0x0f70);  // vmcnt(0) only: my tile-t DMA done
    __syncthreads();                     // all waves' DMA done; prev buf free
    if (t + 1 < nt) stage(k0 + 32, (t + 1) & 1);

    // S^T = K*Q^T: sc[g] rows = keys k0+g*16+quad*4+r, col = q-row l16
    f32x4 sc[2];
#pragma unroll
    for (int g = 0; g < 2; ++g) {
      sc[g] = f32x4{0.f, 0.f, 0.f, 0.f};
#pragma unroll
      for (int c = 0; c < 4; ++c) {
        const s16x8 kf = *(const s16x8*)(
            &Ksc[(g * 16 + l16) * 128 + ((((c << 2) + quad) ^ l16) << 3)]);
        sc[g] = __builtin_amdgcn_mfma_f32_16x16x32_bf16(kf, qf[c], sc[g], 0, 0, 0);
      }
    }
    if (k0 + 31 > qbase) {  // tile may cross the diagonal (wave-uniform branch)
      const int qrow = qbase + l16;
#pragma unroll
      for (int g = 0; g < 2; ++g) {
        const int keyb = k0 + g * 16 + quad * 4;
#pragma unroll
        for (int r = 0; r < 4; ++r)
          if (keyb + r > qrow) sc[g][r] = -1e30f;
      }
    }
    // online softmax (exp2 domain): keys live in regs + across quads
    float mx = fmaxf(fmaxf(fmaxf(sc[0][0], sc[0][1]), fmaxf(sc[0][2], sc[0][3])),
                     fmaxf(fmaxf(sc[1][0], sc[1][1]), fmaxf(sc[1][2], sc[1][3])));
    mx = fmaxf(mx, __shfl_xor(mx, 16, 64));
    mx = fmaxf(mx, __shfl_xor(mx, 32, 64));
    const float mnew = fmaxf(mrun, mx);
    const float alpha = exp2f(mrun - mnew);
    mrun = mnew;
    float p[2][4];
    float sm = 0.f;
#pragma unroll
    for (int g = 0; g < 2; ++g)
#pragma unroll
      for (int r = 0; r < 4; ++r) { p[g][r] = exp2f(sc[g][r] - mnew); sm += p[g][r]; }
    sm += __shfl_xor(sm, 16, 64);
    sm += __shfl_xor(sm, 32, 64);
    lrun = lrun * alpha + sm;
#pragma unroll
    for (int d = 0; d < 8; ++d)
#pragma unroll
      for (int r = 0; r < 4; ++r) acc[d][r] *= alpha;

    // quad-exchange P (S^T C-layout) -> PV B-frag P[n=qrow l16][k=key quad*8+j].
    // dest (quad,j): src lane 32*(quad&1)+l16 (+16 for j>=4), frag g=quad>>1, reg j&3.
    u32 pk[2][2];
#pragma unroll
    for (int g = 0; g < 2; ++g) {
      pk[g][0] = (u32)f2bf(p[g][0]) | ((u32)f2bf(p[g][1]) << 16);
      pk[g][1] = (u32)f2bf(p[g][2]) | ((u32)f2bf(p[g][3]) << 16);
    }
    const int la = ((quad & 1) << 5) + l16;
    const int lb = la + 16;
    const u32 a0 = (u32)__shfl((int)pk[0][0], la, 64);
    const u32 a1 = (u32)__shfl((int)pk[0][1], la, 64);
    const u32 a2 = (u32)__shfl((int)pk[0][0], lb, 64);
    const u32 a3 = (u32)__shfl((int)pk[0][1], lb, 64);
    const u32 b0 = (u32)__shfl((int)pk[1][0], la, 64);
    const u32 b1 = (u32)__shfl((int)pk[1][1], la, 64);
    const u32 b2 = (u32)__shfl((int)pk[1][0], lb, 64);
    const u32 b3 = (u32)__shfl((int)pk[1][1], lb, 64);
    const bool hi = quad >= 2;
    const u32x4 pw = {hi ? b0 : a0, hi ? b1 : a1, hi ? b2 : a2, hi ? b3 : a3};
    const s16x8 pf = __builtin_bit_cast(s16x8, pw);

    // PV: out^T += V^T * P  (A = V^T[m=dim][k=key], B = P[n=qrow][k=key])
#pragma unroll
    for (int dd = 0; dd < 8; ++dd) {
      const s16x8 vf = *(const s16x8*)(
          &Vsc[(dd * 16 + l16) * 32 + ((quad ^ ((l16 >> 1) & 3)) << 3)]);
      acc[dd] = __builtin_amdgcn_mfma_f32_16x16x32_bf16(vf, pf, acc[dd], 0, 0, 0);
    }
  }

  // epilogue: lane l16 owns q-row qbase+l16; dims dd*16+quad*4+r -> ushort4 stores
  const int b = bh >> 4, h = bh & 15;
  u16* op = out + ((long)b * 2048 + qbase + l16) * 2048 + h * 128;
  const float inv_l = 1.0f / lrun;
#pragma unroll
  for (int dd = 0; dd < 8; ++dd) {
    ushort4 o4;
    o4.x = f2bf(acc[dd][0] * inv_l);
    o4.y = f2bf(acc[dd][1] * inv_l);
    o4.z = f2bf(acc[dd][2] * inv_l);
    o4.w = f2bf(acc[dd][3] * inv_l);
    *(ushort4*)(op + dd * 16 + quad * 4) = o4;
  }
}

extern "C" void kernel_launch(void* const* d_in, const int* in_sizes, int n_in,
                              void* d_out, int out_size, void* d_ws, size_t ws_size,
                              hipStream_t stream) {
  const float* hidden = (const float*)d_in[0];  // [2,2048,2048]
  const float* w_qkv = (const float*)d_in[1];   // [6144,2048]
  const float* w_out = (const float*)d_in[2];   // [2048,2048]
  float* out = (float*)d_out;                   // [2,2048,2048] fp32
  char* ws = (char*)d_ws;

  // workspace layout (112 MB total, all 16B aligned)
  u16* hid_b  = (u16*)(ws + (size_t)0);          // hidden bf16
  u16* wqkv_b = (u16*)(ws + (size_t)16777216);   // w_qkv bf16
  u16* wout_b = (u16*)(ws + (size_t)41943040);   // w_out bf16
  u16* qb     = (u16*)(ws + (size_t)50331648);   // q (unroped) [B,H,S,D]
  u16* kb     = (u16*)(ws + (size_t)67108864);   // k (roped)   [B,H,S,D]
  u16* vb     = (u16*)(ws + (size_t)83886080);   // v^T [B,H,D,S]
  u16* ao     = (u16*)(ws + (size_t)100663296);  // attn out [B,S,E]

  cast3_kernel<<<24576, 256, 0, stream>>>(hidden, hid_b, 2097152,
                                          w_qkv, wqkv_b, 3145728,
                                          w_out, wout_b, 1048576);

  // qkv projection, 256^2 8-phase GEMM with fused split/transpose/k-rope epilogue
  gemm_qkv256_kernel<<<dim3(24, 16), 512, 0, stream>>>(hid_b, wqkv_b, 2048,
                                                       qb, kb, vb);
  // causal flash attention (q-rope + scale in prologue)
  attn_kernel<<<1024, 256, 0, stream>>>(qb, kb, vb, ao);
  // output projection -> fp32 (128^2 R4 structure: 512 blocks packs better here)
  gemm_bt_kernel<0><<<dim3(16, 32), 256, 0, stream>>>(ao, wout_b, 2048, 2048,
                                                      out, nullptr, nullptr, nullptr);
}

// Round 2
// 395.430 us; speedup vs baseline: 1.0162x; 1.0162x over previous
//
#include <hip/hip_runtime.h>

typedef unsigned short u16;
typedef unsigned int u32;
typedef __attribute__((ext_vector_type(4))) float f32x4;
typedef __attribute__((ext_vector_type(8))) short s16x8;
typedef __attribute__((ext_vector_type(4))) unsigned int u32x4;

#define DEVI static __device__ __forceinline__

// B=2, S=2048, E=2048, H=16, D=128, MP=4, local=512; qkv cols: [q(512) v(512) k(512)] x4
// k-rope fused into QKV-GEMM epilogue; q-rope (+ (1/sqrt(128))*log2(e) scale) fused into
// attention prologue; softmax in exp2 domain.

#define ROPE_C (-13.287712379549449f / 32.0f)  // -log2(10000)/32
#define QSCALE 0.12751743f                     // log2(e)/sqrt(128)

DEVI u16 f2bf(float f) {
  u32 u = __float_as_uint(f);
  return (u16)((u + 0x7FFFu + ((u >> 16) & 1u)) >> 16);  // round-to-nearest-even
}
DEVI float bf2f(u16 h) { return __uint_as_float(((u32)h) << 16); }

DEVI void async_copy16(const u16* g, u16* l) {
  // dest = wave-uniform LDS base + lane*16 (gfx950 global_load_lds_dwordx4)
  __builtin_amdgcn_global_load_lds((__attribute__((address_space(1))) void*)g,
                                   (__attribute__((address_space(3))) void*)l, 16, 0, 0);
}

// fused fp32->bf16 cast of all three inputs
__global__ __launch_bounds__(256) void cast3_kernel(
    const float* __restrict__ s0, u16* __restrict__ d0, int n0,
    const float* __restrict__ s1, u16* __restrict__ d1, int n1,
    const float* __restrict__ s2, u16* __restrict__ d2, int n2) {
  int i = blockIdx.x * 256 + threadIdx.x;
  const float* s;
  u16* d;
  if (i < n0) {
    s = s0; d = d0;
  } else if (i < n0 + n1) {
    s = s1; d = d1; i -= n0;
  } else if (i < n0 + n1 + n2) {
    s = s2; d = d2; i -= n0 + n1;
  } else {
    return;
  }
  const float4 v = ((const float4*)s)[i];
  ushort4 o;
  o.x = f2bf(v.x); o.y = f2bf(v.y); o.z = f2bf(v.z); o.w = f2bf(v.w);
  ((ushort4*)d)[i] = o;
}

// C[m,n] = sum_k A[m,k]*B[n,k]; A,B row-major bf16, K contiguous (B^T GEMM).
// 128x128 tile, BK=32, 4 waves 2x2 of 64x64, 16x16x32 MFMA, 4x4 frags/wave.
// R4 structure: A,B staged through 3-deep LDS via global_load_lds w16, XOR-swizzled,
// vmcnt(4) + raw s_barrier in steady state. Used for the output projection (EPI=0).
template <int EPI>
__global__ __launch_bounds__(256, 3) void gemm_bt_kernel(
    const u16* __restrict__ A, const u16* __restrict__ Bm, int K, int N,
    float* __restrict__ C, u16* __restrict__ qo, u16* __restrict__ ko, u16* __restrict__ vo) {
  __shared__ __attribute__((aligned(16))) u16 As[3][128 * 32];  // 8KB each
  __shared__ __attribute__((aligned(16))) u16 Bs[3][128 * 32];  // 8KB each
  const int tid = threadIdx.x;
  const int w = tid >> 6, lane = tid & 63;
  const int quad = lane >> 4, l16 = lane & 15;
  const int wrow = (w >> 1) * 64, wcol = (w & 1) * 64;
  const long tileM = (long)blockIdx.y * 128;
  const long tileN = (long)blockIdx.x * 128;

  f32x4 acc[4][4];
#pragma unroll
  for (int i = 0; i < 4; ++i)
#pragma unroll
    for (int j = 0; j < 4; ++j) acc[i][j] = f32x4{0.f, 0.f, 0.f, 0.f};

  // staging: wave w covers tile rows [w*32, w*32+32) in two 16-row chunks.
  const u16* aptr[2];
  const u16* bptr[2];
  int ldso[2];
#pragma unroll
  for (int c = 0; c < 2; ++c) {
    const int r0 = (w * 2 + c) * 16;
    const int row = r0 + (lane >> 2);
    const int colsw = (((lane & 3) ^ ((row >> 1) & 3)) << 3);
    aptr[c] = A + (tileM + row) * (long)K + colsw;
    bptr[c] = Bm + (tileN + row) * (long)K + colsw;
    ldso[c] = r0 * 32;
  }

  auto stage = [&](int k0, int buf) {
#pragma unroll
    for (int c = 0; c < 2; ++c) {
      async_copy16(aptr[c] + k0, &As[buf][ldso[c]]);
      async_copy16(bptr[c] + k0, &Bs[buf][ldso[c]]);
    }
  };

  stage(0, 0);
  stage(32, 1);

  const int psw = (quad ^ ((l16 >> 1) & 3)) << 3;  // read-side swizzle (lane-constant)

  int bt = 0;
  for (int k0 = 0; k0 < K; k0 += 32) {
    if (k0 + 32 < K)
      __builtin_amdgcn_s_waitcnt(0x0f74);  // vmcnt(4): tile t landed, t+1 in flight
    else
      __builtin_amdgcn_s_waitcnt(0x0f70);  // last tile: vmcnt(0)
    __builtin_amdgcn_s_barrier();          // raw barrier: no compiler-forced drain
    if (k0 + 64 < K) stage(k0 + 64, bt == 0 ? 2 : bt - 1);

    s16x8 af[4], bfr[4];
#pragma unroll
    for (int i = 0; i < 4; ++i)
      af[i] = *(const s16x8*)(&As[bt][(wrow + i * 16 + l16) * 32 + psw]);
#pragma unroll
    for (int j = 0; j < 4; ++j)
      bfr[j] = *(const s16x8*)(&Bs[bt][(wcol + j * 16 + l16) * 32 + psw]);
#pragma unroll
    for (int i = 0; i < 4; ++i)
#pragma unroll
      for (int j = 0; j < 4; ++j)
        acc[i][j] = __builtin_amdgcn_mfma_f32_16x16x32_bf16(af[i], bfr[j], acc[i][j], 0, 0, 0);
    bt = bt == 2 ? 0 : bt + 1;
  }

  // ---- inline epilogue ----
  const int b = (int)(tileM >> 11);
#pragma unroll
  for (int i = 0; i < 4; ++i) {
#pragma unroll
    for (int j = 0; j < 4; ++j) {
      const int rowb = (int)((tileM + wrow + i * 16 + quad * 4) & 2047);
      if (EPI == 0) {
#pragma unroll
        for (int r = 0; r < 4; ++r) {
          const long row = tileM + wrow + i * 16 + quad * 4 + r;
          C[row * N + tileN + wcol + j * 16 + l16] = acc[i][j][r];
        }
      } else {
        const long col0 = tileN + wcol + j * 16;
        const int mp = (int)(col0 / 1536);
        const int cc0 = (int)(col0 - (long)mp * 1536);
        const int part = cc0 >> 9;
        const int idx0 = cc0 & 511;
        const int head = mp * 4 + (idx0 >> 7);
        const int dim0 = idx0 & 127;
        const int dim = dim0 + l16;
        const long bh = (long)(b * 16 + head);
        if (part == 1) {
#pragma unroll
          for (int r = 0; r < 4; ++r)
            vo[(bh * 128 + dim) * 2048 + rowb + r] = f2bf(acc[i][j][r]);
        } else {
          float y[4];
          if (part == 2 && dim0 < 64) {
            const int jj = dim >> 1;
            const float inv = exp2f((float)jj * ROPE_C);
#pragma unroll
            for (int r = 0; r < 4; ++r) {
              const float v = acc[i][j][r];
              const float pv = __shfl_xor(v, 1, 64);
              const float ang = (float)(rowb + r) * inv;
              const float sn = __sinf(ang), cs = __cosf(ang);
              y[r] = (l16 & 1) ? (v * cs + pv * sn) : (v * cs - pv * sn);
            }
          } else {
#pragma unroll
            for (int r = 0; r < 4; ++r) y[r] = acc[i][j][r];
          }
          u16* dst = (part == 0) ? qo : ko;
#pragma unroll
          for (int r = 0; r < 4; ++r)
            dst[(bh * 2048 + rowb + r) * 128 + dim] = f2bf(y[r]);
        }
      }
    }
  }
}

// QKV projection: 256x256 tile, BK=64, 8 waves (2M x 4N, 512 thr), 4-phase/K-tile
// schedule (m201-style). R2 fixes vs R1: (1) kk hoisted OUTERMOST in every MFMA
// cluster -- consecutive MFMAs hit distinct accumulators (dependency distance 8,
// was 1: kk-innermost made every 2nd MFMA stall on its predecessor's latency);
// (2) phase bodies ordered ds_read -> stage-issue -> barrier (template order);
// (3) bijective XCD swizzle, B-panel-major chunks (48 blocks/XCD share 3 B panels
// = 3MB, fits 4MB XCD L2). Accumulation order per acc unchanged -> bit-identical.
// Fused epilogue: scatter q / k(roped) / v^T.
__global__ __launch_bounds__(512, 2) void gemm_qkv256_kernel(
    const u16* __restrict__ A, const u16* __restrict__ Bm, int K,
    u16* __restrict__ qo, u16* __restrict__ ko, u16* __restrict__ vo) {
  __shared__ __attribute__((aligned(16))) u16 As[2][2][128 * 64];  // 64KB
  __shared__ __attribute__((aligned(16))) u16 Bs[2][2][128 * 64];  // 64KB
  const int tid = threadIdx.x;
  const int w = tid >> 6, lane = tid & 63;
  const int quad = lane >> 4, l16 = lane & 15;
  const int wm = w >> 2, wn = w & 3;  // wave tile: rows [wm*128,+128), cols [wn*64,+64)

  // XCD swizzle: grid 384 (16 M x 24 N), 384%8==0 -> simple bijective form.
  // id runs N-major-in-chunk: 48 consecutive ids = 3 N-panels x 16 M -> per-XCD L2
  // holds the 3 B panels (3MB), A streams via L3.
  const int bid = blockIdx.x;
  const int id = (bid & 7) * 48 + (bid >> 3);
  const long tileM = (long)(id & 15) * 256;
  const long tileN = (long)(id >> 4) * 256;

  f32x4 acc[8][4];
#pragma unroll
  for (int i = 0; i < 8; ++i)
#pragma unroll
    for (int j = 0; j < 4; ++j) acc[i][j] = f32x4{0.f, 0.f, 0.f, 0.f};

  // staging: per half-tile (128 rows), wave w covers rows [w*16, w*16+16) as 2 loads
  // of 8 rows; lane -> row w*16+c*8+(lane>>3), granule (lane&7)^(row&7) (inverse swz).
  const int rowoff = lane >> 3;                 // 0..7 == row&7 of the staged row
  const int swz = ((lane & 7) ^ rowoff) << 3;   // u16 offset within 64-col row
  const u16* aBase = A + (tileM + w * 16 + rowoff) * (long)K + swz;
  const u16* bBase = Bm + (tileN + w * 16 + rowoff) * (long)K + swz;
  const int ldsb = (w * 16) * 64;

  auto stageA2 = [&](int t) {  // both A halves of tile t: 4 loads
    const int buf = t & 1;
    const long k0 = (long)t << 6;
#pragma unroll
    for (int h = 0; h < 2; ++h)
#pragma unroll
      for (int c = 0; c < 2; ++c)
        async_copy16(aBase + (long)(h * 128 + c * 8) * K + k0,
                     &As[buf][h][ldsb + c * 8 * 64]);
  };
  auto stageB2 = [&](int t) {  // both B halves of tile t: 4 loads
    const int buf = t & 1;
    const long k0 = (long)t << 6;
#pragma unroll
    for (int h = 0; h < 2; ++h)
#pragma unroll
      for (int c = 0; c < 2; ++c)
        async_copy16(bBase + (long)(h * 128 + c * 8) * K + k0,
                     &Bs[buf][h][ldsb + c * 8 * 64]);
  };

  const int gsw = l16 & 7;  // read-side granule XOR (row&7 == l16&7 for frag rows)
  auto rdA = [&](int buf, int i, int kk) -> s16x8 {  // i: 0..7 local m-frag
    return *(const s16x8*)(
        &As[buf][wm][(i * 16 + l16) * 64 + ((((kk << 2) + quad) ^ gsw) << 3)]);
  };
  auto rdB = [&](int buf, int j, int kk) -> s16x8 {  // j: 0..3 local n-frag
    return *(const s16x8*)(
        &Bs[buf][wn >> 1][(((wn & 1) * 64) + j * 16 + l16) * 64 +
                          ((((kk << 2) + quad) ^ gsw) << 3)]);
  };

  const int NT = K >> 6;
  // prologue: tiles 0 and 1 (per-tile issue order B(4),A(4) matches main loop)
  stageB2(0); stageA2(0);
  stageB2(1); stageA2(1);
  __builtin_amdgcn_s_waitcnt(0x0f78);  // vmcnt(8): tile 0 landed, tile 1 in flight
  __builtin_amdgcn_s_barrier();

  for (int t = 0; t < NT; ++t) {
    const int buf = t & 1;
    const bool pf = (t + 2 < NT);
    s16x8 a[4][2], b0[2][2], b1[2][2];

    // ---- phase 1: A-half(local rows 0..63) + B cols 0..31 -> Q(0,0)
#pragma unroll
    for (int i = 0; i < 4; ++i)
#pragma unroll
      for (int kk = 0; kk < 2; ++kk) a[i][kk] = rdA(buf, i, kk);
#pragma unroll
    for (int j = 0; j < 2; ++j)
#pragma unroll
      for (int kk = 0; kk < 2; ++kk) b0[j][kk] = rdB(buf, j, kk);
    __builtin_amdgcn_s_barrier();
    __builtin_amdgcn_s_setprio(1);
#pragma unroll
    for (int kk = 0; kk < 2; ++kk)
#pragma unroll
      for (int i = 0; i < 4; ++i)
#pragma unroll
        for (int j = 0; j < 2; ++j)
          acc[i][j] =
              __builtin_amdgcn_mfma_f32_16x16x32_bf16(a[i][kk], b0[j][kk], acc[i][j], 0, 0, 0);
    __builtin_amdgcn_s_setprio(0);
    __builtin_amdgcn_s_barrier();

    // ---- phase 2: B cols 32..63 -> Q(0,1)
#pragma unroll
    for (int j = 0; j < 2; ++j)
#pragma unroll
      for (int kk = 0; kk < 2; ++kk) b1[j][kk] = rdB(buf, 2 + j, kk);
    __builtin_amdgcn_s_barrier();
    __builtin_amdgcn_s_setprio(1);
#pragma unroll
    for (int kk = 0; kk < 2; ++kk)
#pragma unroll
      for (int i = 0; i < 4; ++i)
#pragma unroll
        for (int j = 0; j < 2; ++j)
          acc[i][2 + j] = __builtin_amdgcn_mfma_f32_16x16x32_bf16(a[i][kk], b1[j][kk],
                                                                  acc[i][2 + j], 0, 0, 0);
    __builtin_amdgcn_s_setprio(0);
    __builtin_amdgcn_s_barrier();

    // ---- phase 3: A rows 64..127; stage B(t+2) [B slots of this buf fully read]
#pragma unroll
    for (int i = 0; i < 4; ++i)
#pragma unroll
      for (int kk = 0; kk < 2; ++kk) a[i][kk] = rdA(buf, 4 + i, kk);
    if (pf) stageB2(t + 2);
    __builtin_amdgcn_s_barrier();
    __builtin_amdgcn_s_setprio(1);
#pragma unroll
    for (int kk = 0; kk < 2; ++kk)
#pragma unroll
      for (int i = 0; i < 4; ++i)
#pragma unroll
        for (int j = 0; j < 2; ++j)
          acc[4 + i][j] = __builtin_amdgcn_mfma_f32_16x16x32_bf16(a[i][kk], b0[j][kk],
                                                                  acc[4 + i][j], 0, 0, 0);
    __builtin_amdgcn_s_setprio(0);
    __builtin_amdgcn_s_barrier();

    // ---- phase 4: stage A(t+2) [A slots fully read]; -> Q(1,1); counted vmcnt
    if (pf) stageA2(t + 2);
    __builtin_amdgcn_s_barrier();
    __builtin_amdgcn_s_setprio(1);
#pragma unroll
    for (int kk = 0; kk < 2; ++kk)
#pragma unroll
      for (int i = 0; i < 4; ++i)
#pragma unroll
        for (int j = 0; j < 2; ++j)
          acc[4 + i][2 + j] = __builtin_amdgcn_mfma_f32_16x16x32_bf16(
              a[i][kk], b1[j][kk], acc[4 + i][2 + j], 0, 0, 0);
    __builtin_amdgcn_s_setprio(0);
    if (pf)
      __builtin_amdgcn_s_waitcnt(0x0f78);  // vmcnt(8): only this tile's stages in flight
    else
      __builtin_amdgcn_s_waitcnt(0x0f70);  // tail: drain
    __builtin_amdgcn_s_barrier();
  }

  // ---- fused scatter epilogue (same mapping as gemm_bt_kernel<1>) ----
  const int b = (int)(tileM >> 11);  // 256-row tile never straddles batch
#pragma unroll
  for (int i = 0; i < 8; ++i) {
#pragma unroll
    for (int j = 0; j < 4; ++j) {
      const int rowb = (int)((tileM + wm * 128 + i * 16 + quad * 4) & 2047);
      const long col0 = tileN + wn * 64 + j * 16;  // wave-uniform base col of this frag
      const int mp = (int)(col0 / 1536);
      const int cc0 = (int)(col0 - (long)mp * 1536);
      const int part = cc0 >> 9;  // 0:q 1:v 2:k (uniform per frag)
      const int idx0 = cc0 & 511;
      const int head = mp * 4 + (idx0 >> 7);
      const int dim0 = idx0 & 127;
      const int dim = dim0 + l16;
      const long bh = (long)(b * 16 + head);
      if (part == 1) {
#pragma unroll
        for (int r = 0; r < 4; ++r)
          vo[(bh * 128 + dim) * 2048 + rowb + r] = f2bf(acc[i][j][r]);  // v^T
      } else {
        float y[4];
        if (part == 2 && dim0 < 64) {
          // k-rope: pair partner is adjacent lane (col parity == l16 parity)
          const int jj = dim >> 1;
          const float inv = exp2f((float)jj * ROPE_C);
#pragma unroll
          for (int r = 0; r < 4; ++r) {
            const float v = acc[i][j][r];
            const float pv = __shfl_xor(v, 1, 64);
            const float ang = (float)(rowb + r) * inv;
            const float sn = __sinf(ang), cs = __cosf(ang);
            y[r] = (l16 & 1) ? (v * cs + pv * sn) : (v * cs - pv * sn);
          }
        } else {
#pragma unroll
          for (int r = 0; r < 4; ++r) y[r] = acc[i][j][r];
        }
        u16* dst = (part == 0) ? qo : ko;
#pragma unroll
        for (int r = 0; r < 4; ++r)
          dst[(bh * 2048 + rowb + r) * 128 + dim] = f2bf(y[r]);
      }
    }
  }
}

// Flash attention v4.1: swapped-operand design. Block = 64 q rows (4 waves x 16 rows),
// 32-key LDS tiles (4 blocks/CU). S^T = K*Q^T (A=K, B=Q): each lane holds 8 scores of
// ONE q-row (keys in regs) -> softmax reduce = in-lane + 2 shfl; m/l scalars per lane;
// P enters PV as B-operand via an 8-shfl quad-exchange (no LDS round-trip);
// PV = V^T*P gives out^T whose stores vectorize as ushort4. Heavy-first grid.
// R2 grafts: setprio around MFMA clusters (T5); defer-max THR=8 in exp2 domain (T13);
// QK^T g-interleave (dependency distance 2, was a 4-chain per sc[g]); raw s_barrier
// after explicit vmcnt(0) (drops __syncthreads' redundant full drain).
__global__ __launch_bounds__(256, 4) void attn_kernel(
    const u16* __restrict__ q, const u16* __restrict__ k,
    const u16* __restrict__ vT, u16* __restrict__ out) {
  __shared__ __attribute__((aligned(16))) u16 Ks[2][32 * 128];  // 8KB each
  __shared__ __attribute__((aligned(16))) u16 Vs[2][128 * 32];  // 8KB each
  const int tid = threadIdx.x;
  const int w = tid >> 6, lane = tid & 63;
  const int quad = lane >> 4, l16 = lane & 15;
  const int qt = 31 - (blockIdx.x >> 5);  // heavy tiles dispatched first
  const int bh = blockIdx.x & 31;
  const int qbase = qt * 64 + w * 16;

  const u16* qp = q + ((long)bh * 2048 + qbase) * 128;
  const u16* kp = k + (long)bh * 2048 * 128;
  const u16* vp = vT + (long)bh * 128 * 2048;

  // Q B-frag: Q[n=l16][kdim = c*32 + quad*8 + j], roped + scaled in fp32
  const float spos = (float)(qbase + l16);
  s16x8 qf[4];
#pragma unroll
  for (int c = 0; c < 4; ++c) {
    const s16x8 raw = *(const s16x8*)(qp + l16 * 128 + c * 32 + quad * 8);
    s16x8 ov;
    if (c < 2) {  // dims < 64: rotate pairs (in-lane: 2m, 2m+1)
#pragma unroll
      for (int m = 0; m < 4; ++m) {
        const int jj = c * 16 + quad * 4 + m;
        const float inv = exp2f((float)jj * ROPE_C);
        const float ang = spos * inv;
        const float sn = __sinf(ang), cs = __cosf(ang);
        const float x0 = bf2f((u16)raw[2 * m]), x1 = bf2f((u16)raw[2 * m + 1]);
        ov[2 * m] = (short)f2bf((x0 * cs - x1 * sn) * QSCALE);
        ov[2 * m + 1] = (short)f2bf((x1 * cs + x0 * sn) * QSCALE);
      }
    } else {      // dims >= 64: pass-through, scale only
#pragma unroll
      for (int e = 0; e < 8; ++e) ov[e] = (short)f2bf(bf2f((u16)raw[e]) * QSCALE);
    }
    qf[c] = ov;
  }

  f32x4 acc[8];  // out^T: acc[dd] rows = dims dd*16+quad*4+r, col = q-row l16
#pragma unroll
  for (int d = 0; d < 8; ++d) acc[d] = f32x4{0.f, 0.f, 0.f, 0.f};
  float mrun = -1e30f, lrun = 0.f;  // per-lane scalars (q-row = qbase+l16)

  // stage one 32-key tile: wave w stages keys [w*8,w*8+8) and dims [w*32,w*32+32)
  auto stage = [&](int k0, int buf) {
    const int ko = lane >> 4, cl = lane & 15;
#pragma unroll
    for (int i = 0; i < 2; ++i) {
      const int keyt = w * 8 + i * 4;
      const int key = keyt + ko;
      async_copy16(kp + (long)(k0 + key) * 128 + ((cl ^ (key & 15)) << 3),
                   &Ks[buf][keyt * 128]);
    }
    const int ld = lane >> 2, c4 = lane & 3;
#pragma unroll
    for (int i = 0; i < 2; ++i) {
      const int db = w * 32 + i * 16;
      const int d = db + ld;
      async_copy16(vp + (long)d * 2048 + k0 + ((c4 ^ ((d >> 1) & 3)) << 3),
                   &Vs[buf][db * 32]);
    }
  };

  stage(0, 0);

  const int nt = 2 * qt + 2;
  for (int t = 0; t < nt; ++t) {
    const int k0 = t * 32;
    const u16* Ksc = Ks[t & 1];
    const u16* Vsc = Vs[t & 1];
    __builtin_amdgcn_s_waitcnt(0x0f70);  // vmcnt(0): my tile-t DMA done
    __builtin_amdgcn_s_barrier();        // all waves' DMA done; prev buf free
    if (t + 1 < nt) stage(k0 + 32, (t + 1) & 1);

    // S^T = K*Q^T: sc[g] rows = keys k0+g*16+quad*4+r, col = q-row l16.
    // g interleaved inside c: consecutive MFMAs independent (per-sc order unchanged).
    f32x4 sc[2];
    sc[0] = f32x4{0.f, 0.f, 0.f, 0.f};
    sc[1] = f32x4{0.f, 0.f, 0.f, 0.f};
    __builtin_amdgcn_s_setprio(1);
#pragma unroll
    for (int c = 0; c < 4; ++c) {
      const s16x8 kf0 = *(const s16x8*)(
          &Ksc[(0 * 16 + l16) * 128 + ((((c << 2) + quad) ^ l16) << 3)]);
      const s16x8 kf1 = *(const s16x8*)(
          &Ksc[(1 * 16 + l16) * 128 + ((((c << 2) + quad) ^ l16) << 3)]);
      sc[0] = __builtin_amdgcn_mfma_f32_16x16x32_bf16(kf0, qf[c], sc[0], 0, 0, 0);
      sc[1] = __builtin_amdgcn_mfma_f32_16x16x32_bf16(kf1, qf[c], sc[1], 0, 0, 0);
    }
    __builtin_amdgcn_s_setprio(0);
    if (k0 + 31 > qbase) {  // tile may cross the diagonal (wave-uniform branch)
      const int qrow = qbase + l16;
#pragma unroll
      for (int g = 0; g < 2; ++g) {
        const int keyb = k0 + g * 16 + quad * 4;
#pragma unroll
        for (int r = 0; r < 4; ++r)
          if (keyb + r > qrow) sc[g][r] = -1e30f;
      }
    }
    // online softmax (exp2 domain), defer-max (T13): skip the O(acc) rescale while
    // the tile max stays within THR=8 of the running max (P bounded by 2^8).
    float mx = fmaxf(fmaxf(fmaxf(sc[0][0], sc[0][1]), fmaxf(sc[0][2], sc[0][3])),
                     fmaxf(fmaxf(sc[1][0], sc[1][1]), fmaxf(sc[1][2], sc[1][3])));
    mx = fmaxf(mx, __shfl_xor(mx, 16, 64));
    mx = fmaxf(mx, __shfl_xor(mx, 32, 64));
    if (__any(mx > mrun + 8.f)) {  // wave-uniform rescale
      const float mnew = fmaxf(mrun, mx);
      const float alpha = exp2f(mrun - mnew);
      mrun = mnew;
      lrun *= alpha;
#pragma unroll
      for (int d = 0; d < 8; ++d)
#pragma unroll
        for (int r = 0; r < 4; ++r) acc[d][r] *= alpha;
    }
    float p[2][4];
    float sm = 0.f;
#pragma unroll
    for (int g = 0; g < 2; ++g)
#pragma unroll
      for (int r = 0; r < 4; ++r) { p[g][r] = exp2f(sc[g][r] - mrun); sm += p[g][r]; }
    sm += __shfl_xor(sm, 16, 64);
    sm += __shfl_xor(sm, 32, 64);
    lrun += sm;

    // quad-exchange P (S^T C-layout) -> PV B-frag P[n=qrow l16][k=key quad*8+j].
    // dest (quad,j): src lane 32*(quad&1)+l16 (+16 for j>=4), frag g=quad>>1, reg j&3.
    u32 pk[2][2];
#pragma unroll
    for (int g = 0; g < 2; ++g) {
      pk[g][0] = (u32)f2bf(p[g][0]) | ((u32)f2bf(p[g][1]) << 16);
      pk[g][1] = (u32)f2bf(p[g][2]) | ((u32)f2bf(p[g][3]) << 16);
    }
    const int la = ((quad & 1) << 5) + l16;
    const int lb = la + 16;
    const u32 a0 = (u32)__shfl((int)pk[0][0], la, 64);
    const u32 a1 = (u32)__shfl((int)pk[0][1], la, 64);
    const u32 a2 = (u32)__shfl((int)pk[0][0], lb, 64);
    const u32 a3 = (u32)__shfl((int)pk[0][1], lb, 64);
    const u32 b0 = (u32)__shfl((int)pk[1][0], la, 64);
    const u32 b1 = (u32)__shfl((int)pk[1][1], la, 64);
    const u32 b2 = (u32)__shfl((int)pk[1][0], lb, 64);
    const u32 b3 = (u32)__shfl((int)pk[1][1], lb, 64);
    const bool hi = quad >= 2;
    const u32x4 pw = {hi ? b0 : a0, hi ? b1 : a1, hi ? b2 : a2, hi ? b3 : a3};
    const s16x8 pf = __builtin_bit_cast(s16x8, pw);

    // PV: out^T += V^T * P  (A = V^T[m=dim][k=key], B = P[n=qrow][k=key])
    __builtin_amdgcn_s_setprio(1);
#pragma unroll
    for (int dd = 0; dd < 8; ++dd) {
      const s16x8 vf = *(const s16x8*)(
          &Vsc[(dd * 16 + l16) * 32 + ((quad ^ ((l16 >> 1) & 3)) << 3)]);
      acc[dd] = __builtin_amdgcn_mfma_f32_16x16x32_bf16(vf, pf, acc[dd], 0, 0, 0);
    }
    __builtin_amdgcn_s_setprio(0);
  }

  // epilogue: lane l16 owns q-row qbase+l16; dims dd*16+quad*4+r -> ushort4 stores
  const int b = bh >> 4, h = bh & 15;
  u16* op = out + ((long)b * 2048 + qbase + l16) * 2048 + h * 128;
  const float inv_l = 1.0f / lrun;
#pragma unroll
  for (int dd = 0; dd < 8; ++dd) {
    ushort4 o4;
    o4.x = f2bf(acc[dd][0] * inv_l);
    o4.y = f2bf(acc[dd][1] * inv_l);
    o4.z = f2bf(acc[dd][2] * inv_l);
    o4.w = f2bf(acc[dd][3] * inv_l);
    *(ushort4*)(op + dd * 16 + quad * 4) = o4;
  }
}

extern "C" void kernel_launch(void* const* d_in, const int* in_sizes, int n_in,
                              void* d_out, int out_size, void* d_ws, size_t ws_size,
                              hipStream_t stream) {
  const float* hidden = (const float*)d_in[0];  // [2,2048,2048]
  const float* w_qkv = (const float*)d_in[1];   // [6144,2048]
  const float* w_out = (const float*)d_in[2];   // [2048,2048]
  float* out = (float*)d_out;                   // [2,2048,2048] fp32
  char* ws = (char*)d_ws;

  // workspace layout (112 MB total, all 16B aligned)
  u16* hid_b  = (u16*)(ws + (size_t)0);          // hidden bf16
  u16* wqkv_b = (u16*)(ws + (size_t)16777216);   // w_qkv bf16
  u16* wout_b = (u16*)(ws + (size_t)41943040);   // w_out bf16
  u16* qb     = (u16*)(ws + (size_t)50331648);   // q (unroped) [B,H,S,D]
  u16* kb     = (u16*)(ws + (size_t)67108864);   // k (roped)   [B,H,S,D]
  u16* vb     = (u16*)(ws + (size_t)83886080);   // v^T [B,H,D,S]
  u16* ao     = (u16*)(ws + (size_t)100663296);  // attn out [B,S,E]

  cast3_kernel<<<24576, 256, 0, stream>>>(hidden, hid_b, 2097152,
                                          w_qkv, wqkv_b, 3145728,
                                          w_out, wout_b, 1048576);

  // qkv projection, 256^2 4-phase GEMM with fused split/transpose/k-rope epilogue
  gemm_qkv256_kernel<<<384, 512, 0, stream>>>(hid_b, wqkv_b, 2048, qb, kb, vb);
  // causal flash attention (q-rope + scale in prologue)
  attn_kernel<<<1024, 256, 0, stream>>>(qb, kb, vb, ao);
  // output projection -> fp32 (128^2 R4 structure: 512 blocks packs better here)
  gemm_bt_kernel<0><<<dim3(16, 32), 256, 0, stream>>>(ao, wout_b, 2048, 2048,
                                                      out, nullptr, nullptr, nullptr);
}

// Round 3
// 383.846 us; speedup vs baseline: 1.0469x; 1.0302x over previous
//
#include <hip/hip_runtime.h>

typedef unsigned short u16;
typedef unsigned int u32;
typedef __attribute__((ext_vector_type(4))) float f32x4;
typedef __attribute__((ext_vector_type(8))) short s16x8;
typedef __attribute__((ext_vector_type(4))) unsigned int u32x4;

#define DEVI static __device__ __forceinline__

// B=2, S=2048, E=2048, H=16, D=128, MP=4, local=512; qkv cols: [q(512) v(512) k(512)] x4
// k-rope fused into QKV-GEMM epilogue; q-rope (+ (1/sqrt(128))*log2(e) scale) fused into
// attention prologue; softmax in exp2 domain.

#define ROPE_C (-13.287712379549449f / 32.0f)  // -log2(10000)/32
#define QSCALE 0.12751743f                     // log2(e)/sqrt(128)

DEVI u16 f2bf(float f) {
  u32 u = __float_as_uint(f);
  return (u16)((u + 0x7FFFu + ((u >> 16) & 1u)) >> 16);  // round-to-nearest-even
}
DEVI float bf2f(u16 h) { return __uint_as_float(((u32)h) << 16); }

DEVI void async_copy16(const u16* g, u16* l) {
  // dest = wave-uniform LDS base + lane*16 (gfx950 global_load_lds_dwordx4)
  __builtin_amdgcn_global_load_lds((__attribute__((address_space(1))) void*)g,
                                   (__attribute__((address_space(3))) void*)l, 16, 0, 0);
}

// fused fp32->bf16 cast of all three inputs
__global__ __launch_bounds__(256) void cast3_kernel(
    const float* __restrict__ s0, u16* __restrict__ d0, int n0,
    const float* __restrict__ s1, u16* __restrict__ d1, int n1,
    const float* __restrict__ s2, u16* __restrict__ d2, int n2) {
  int i = blockIdx.x * 256 + threadIdx.x;
  const float* s;
  u16* d;
  if (i < n0) {
    s = s0; d = d0;
  } else if (i < n0 + n1) {
    s = s1; d = d1; i -= n0;
  } else if (i < n0 + n1 + n2) {
    s = s2; d = d2; i -= n0 + n1;
  } else {
    return;
  }
  const float4 v = ((const float4*)s)[i];
  ushort4 o;
  o.x = f2bf(v.x); o.y = f2bf(v.y); o.z = f2bf(v.z); o.w = f2bf(v.w);
  ((ushort4*)d)[i] = o;
}

// C[m,n] = sum_k A[m,k]*B[n,k]; A,B row-major bf16, K contiguous (B^T GEMM).
// 128x128 tile, BK=32, 4 waves 2x2 of 64x64, 16x16x32 MFMA, 4x4 frags/wave.
// R4 structure (best measured, 136.5us QKV): A,B staged through 3-deep LDS via
// global_load_lds w16, XOR-swizzled, vmcnt(4) + raw s_barrier in steady state,
// 3 blocks/CU (cross-block overlap hides the barrier drains). Inline epilogue.
// EPI=0: C fp32 store. EPI=1: scatter qkv -> q[B,H,S,D], k(roped)[B,H,S,D], v^T[B,H,D,S].
template <int EPI>
__global__ __launch_bounds__(256, 3) void gemm_bt_kernel(
    const u16* __restrict__ A, const u16* __restrict__ Bm, int K, int N,
    float* __restrict__ C, u16* __restrict__ qo, u16* __restrict__ ko, u16* __restrict__ vo) {
  __shared__ __attribute__((aligned(16))) u16 As[3][128 * 32];  // 8KB each
  __shared__ __attribute__((aligned(16))) u16 Bs[3][128 * 32];  // 8KB each
  const int tid = threadIdx.x;
  const int w = tid >> 6, lane = tid & 63;
  const int quad = lane >> 4, l16 = lane & 15;
  const int wrow = (w >> 1) * 64, wcol = (w & 1) * 64;
  const long tileM = (long)blockIdx.y * 128;
  const long tileN = (long)blockIdx.x * 128;

  f32x4 acc[4][4];
#pragma unroll
  for (int i = 0; i < 4; ++i)
#pragma unroll
    for (int j = 0; j < 4; ++j) acc[i][j] = f32x4{0.f, 0.f, 0.f, 0.f};

  // staging: wave w covers tile rows [w*32, w*32+32) in two 16-row chunks.
  const u16* aptr[2];
  const u16* bptr[2];
  int ldso[2];
#pragma unroll
  for (int c = 0; c < 2; ++c) {
    const int r0 = (w * 2 + c) * 16;
    const int row = r0 + (lane >> 2);
    const int colsw = (((lane & 3) ^ ((row >> 1) & 3)) << 3);
    aptr[c] = A + (tileM + row) * (long)K + colsw;
    bptr[c] = Bm + (tileN + row) * (long)K + colsw;
    ldso[c] = r0 * 32;
  }

  auto stage = [&](int k0, int buf) {
#pragma unroll
    for (int c = 0; c < 2; ++c) {
      async_copy16(aptr[c] + k0, &As[buf][ldso[c]]);
      async_copy16(bptr[c] + k0, &Bs[buf][ldso[c]]);
    }
  };

  stage(0, 0);
  stage(32, 1);

  const int psw = (quad ^ ((l16 >> 1) & 3)) << 3;  // read-side swizzle (lane-constant)

  int bt = 0;
  for (int k0 = 0; k0 < K; k0 += 32) {
    if (k0 + 32 < K)
      __builtin_amdgcn_s_waitcnt(0x0f74);  // vmcnt(4): tile t landed, t+1 in flight
    else
      __builtin_amdgcn_s_waitcnt(0x0f70);  // last tile: vmcnt(0)
    __builtin_amdgcn_s_barrier();          // raw barrier: no compiler-forced drain
    if (k0 + 64 < K) stage(k0 + 64, bt == 0 ? 2 : bt - 1);

    s16x8 af[4], bfr[4];
#pragma unroll
    for (int i = 0; i < 4; ++i)
      af[i] = *(const s16x8*)(&As[bt][(wrow + i * 16 + l16) * 32 + psw]);
#pragma unroll
    for (int j = 0; j < 4; ++j)
      bfr[j] = *(const s16x8*)(&Bs[bt][(wcol + j * 16 + l16) * 32 + psw]);
#pragma unroll
    for (int i = 0; i < 4; ++i)
#pragma unroll
      for (int j = 0; j < 4; ++j)
        acc[i][j] = __builtin_amdgcn_mfma_f32_16x16x32_bf16(af[i], bfr[j], acc[i][j], 0, 0, 0);
    bt = bt == 2 ? 0 : bt + 1;
  }

  // ---- inline epilogue (single call site; acc stays in registers) ----
  const int b = (int)(tileM >> 11);  // 128-row tile never straddles batch
#pragma unroll
  for (int i = 0; i < 4; ++i) {
#pragma unroll
    for (int j = 0; j < 4; ++j) {
      const int rowb = (int)((tileM + wrow + i * 16 + quad * 4) & 2047);  // s of reg 0
      if (EPI == 0) {
#pragma unroll
        for (int r = 0; r < 4; ++r) {
          const long row = tileM + wrow + i * 16 + quad * 4 + r;
          C[row * N + tileN + wcol + j * 16 + l16] = acc[i][j][r];
        }
      } else {
        const long col0 = tileN + wcol + j * 16;  // wave-uniform base col of this frag
        const int mp = (int)(col0 / 1536);
        const int cc0 = (int)(col0 - (long)mp * 1536);
        const int part = cc0 >> 9;     // 0:q 1:v 2:k (uniform per frag)
        const int idx0 = cc0 & 511;
        const int head = mp * 4 + (idx0 >> 7);
        const int dim0 = idx0 & 127;
        const int dim = dim0 + l16;
        const long bh = (long)(b * 16 + head);
        if (part == 1) {
#pragma unroll
          for (int r = 0; r < 4; ++r)
            vo[(bh * 128 + dim) * 2048 + rowb + r] = f2bf(acc[i][j][r]);  // v^T
        } else {
          float y[4];
          if (part == 2 && dim0 < 64) {
            // k-rope: pair partner is adjacent lane (col parity == l16 parity)
            const int jj = dim >> 1;
            const float inv = exp2f((float)jj * ROPE_C);
#pragma unroll
            for (int r = 0; r < 4; ++r) {
              const float v = acc[i][j][r];
              const float pv = __shfl_xor(v, 1, 64);
              const float ang = (float)(rowb + r) * inv;
              const float sn = __sinf(ang), cs = __cosf(ang);
              y[r] = (l16 & 1) ? (v * cs + pv * sn) : (v * cs - pv * sn);
            }
          } else {
#pragma unroll
            for (int r = 0; r < 4; ++r) y[r] = acc[i][j][r];
          }
          u16* dst = (part == 0) ? qo : ko;
#pragma unroll
          for (int r = 0; r < 4; ++r)
            dst[(bh * 2048 + rowb + r) * 128 + dim] = f2bf(y[r]);
        }
      }
    }
  }
}

// Flash attention v4.2: swapped-operand design. Block = 64 q rows (4 waves x 16 rows),
// 32-key tiles. S^T = K*Q^T (A=K, B=Q): each lane holds 8 scores of ONE q-row (keys in
// regs) -> softmax reduce = in-lane + 2 shfl; m/l scalars per lane; P enters PV as
// B-operand via an 8-shfl quad-exchange (no LDS round-trip); PV = V^T*P gives out^T
// whose stores vectorize as ushort4. Heavy-first grid.
// R3: 3-deep LDS ring + counted vmcnt(4) (per-wave: 4 DMAs/tile) -- stage(t+2) issued
// at top of tile t, so ~2 tile bodies of HBM-latency cover instead of <1 with the old
// 2-buffer vmcnt(0) scheme (which drained the in-flight tile every iteration).
// LDS 48KB -> 3 blocks/CU. Buffer safety: stage(t+2) writes buf (t-1)%3; the top-of-t
// barrier proves all waves finished reading it (same argument as the R4 GEMM ring).
// Keeps R2 grafts: setprio around MFMA clusters (T5), defer-max THR=8 (T13),
// QK^T g-interleave, raw s_barrier after explicit vmcnt.
__global__ __launch_bounds__(256, 3) void attn_kernel(
    const u16* __restrict__ q, const u16* __restrict__ k,
    const u16* __restrict__ vT, u16* __restrict__ out) {
  __shared__ __attribute__((aligned(16))) u16 Ks[3][32 * 128];  // 8KB each
  __shared__ __attribute__((aligned(16))) u16 Vs[3][128 * 32];  // 8KB each
  const int tid = threadIdx.x;
  const int w = tid >> 6, lane = tid & 63;
  const int quad = lane >> 4, l16 = lane & 15;
  const int qt = 31 - (blockIdx.x >> 5);  // heavy tiles dispatched first
  const int bh = blockIdx.x & 31;
  const int qbase = qt * 64 + w * 16;

  const u16* qp = q + ((long)bh * 2048 + qbase) * 128;
  const u16* kp = k + (long)bh * 2048 * 128;
  const u16* vp = vT + (long)bh * 128 * 2048;

  // Q B-frag: Q[n=l16][kdim = c*32 + quad*8 + j], roped + scaled in fp32
  const float spos = (float)(qbase + l16);
  s16x8 qf[4];
#pragma unroll
  for (int c = 0; c < 4; ++c) {
    const s16x8 raw = *(const s16x8*)(qp + l16 * 128 + c * 32 + quad * 8);
    s16x8 ov;
    if (c < 2) {  // dims < 64: rotate pairs (in-lane: 2m, 2m+1)
#pragma unroll
      for (int m = 0; m < 4; ++m) {
        const int jj = c * 16 + quad * 4 + m;
        const float inv = exp2f((float)jj * ROPE_C);
        const float ang = spos * inv;
        const float sn = __sinf(ang), cs = __cosf(ang);
        const float x0 = bf2f((u16)raw[2 * m]), x1 = bf2f((u16)raw[2 * m + 1]);
        ov[2 * m] = (short)f2bf((x0 * cs - x1 * sn) * QSCALE);
        ov[2 * m + 1] = (short)f2bf((x1 * cs + x0 * sn) * QSCALE);
      }
    } else {      // dims >= 64: pass-through, scale only
#pragma unroll
      for (int e = 0; e < 8; ++e) ov[e] = (short)f2bf(bf2f((u16)raw[e]) * QSCALE);
    }
    qf[c] = ov;
  }

  f32x4 acc[8];  // out^T: acc[dd] rows = dims dd*16+quad*4+r, col = q-row l16
#pragma unroll
  for (int d = 0; d < 8; ++d) acc[d] = f32x4{0.f, 0.f, 0.f, 0.f};
  float mrun = -1e30f, lrun = 0.f;  // per-lane scalars (q-row = qbase+l16)

  // stage one 32-key tile: wave w stages keys [w*8,w*8+8) and dims [w*32,w*32+32);
  // exactly 4 async DMAs per wave per tile (vmcnt counts per-wave).
  auto stage = [&](int k0, int buf) {
    const int ko = lane >> 4, cl = lane & 15;
#pragma unroll
    for (int i = 0; i < 2; ++i) {
      const int keyt = w * 8 + i * 4;
      const int key = keyt + ko;
      async_copy16(kp + (long)(k0 + key) * 128 + ((cl ^ (key & 15)) << 3),
                   &Ks[buf][keyt * 128]);
    }
    const int ld = lane >> 2, c4 = lane & 3;
#pragma unroll
    for (int i = 0; i < 2; ++i) {
      const int db = w * 32 + i * 16;
      const int d = db + ld;
      async_copy16(vp + (long)d * 2048 + k0 + ((c4 ^ ((d >> 1) & 3)) << 3),
                   &Vs[buf][db * 32]);
    }
  };

  const int nt = 2 * qt + 2;  // nt >= 2 always
  stage(0, 0);
  stage(32, 1);

  int bt = 0;
  for (int t = 0; t < nt; ++t) {
    const int k0 = t * 32;
    if (t + 1 < nt)
      __builtin_amdgcn_s_waitcnt(0x0f74);  // vmcnt(4): tile t landed, t+1 in flight
    else
      __builtin_amdgcn_s_waitcnt(0x0f70);  // last tile: vmcnt(0)
    __builtin_amdgcn_s_barrier();          // all waves' tile-t DMA done; buf t-1 free
    if (t + 2 < nt) stage(k0 + 64, bt == 0 ? 2 : bt - 1);
    const u16* Ksc = Ks[bt];
    const u16* Vsc = Vs[bt];

    // S^T = K*Q^T: sc[g] rows = keys k0+g*16+quad*4+r, col = q-row l16.
    // g interleaved inside c: consecutive MFMAs independent (per-sc order unchanged).
    f32x4 sc[2];
    sc[0] = f32x4{0.f, 0.f, 0.f, 0.f};
    sc[1] = f32x4{0.f, 0.f, 0.f, 0.f};
    __builtin_amdgcn_s_setprio(1);
#pragma unroll
    for (int c = 0; c < 4; ++c) {
      const s16x8 kf0 = *(const s16x8*)(
          &Ksc[(0 * 16 + l16) * 128 + ((((c << 2) + quad) ^ l16) << 3)]);
      const s16x8 kf1 = *(const s16x8*)(
          &Ksc[(1 * 16 + l16) * 128 + ((((c << 2) + quad) ^ l16) << 3)]);
      sc[0] = __builtin_amdgcn_mfma_f32_16x16x32_bf16(kf0, qf[c], sc[0], 0, 0, 0);
      sc[1] = __builtin_amdgcn_mfma_f32_16x16x32_bf16(kf1, qf[c], sc[1], 0, 0, 0);
    }
    __builtin_amdgcn_s_setprio(0);
    if (k0 + 31 > qbase) {  // tile may cross the diagonal (wave-uniform branch)
      const int qrow = qbase + l16;
#pragma unroll
      for (int g = 0; g < 2; ++g) {
        const int keyb = k0 + g * 16 + quad * 4;
#pragma unroll
        for (int r = 0; r < 4; ++r)
          if (keyb + r > qrow) sc[g][r] = -1e30f;
      }
    }
    // online softmax (exp2 domain), defer-max (T13): skip the O(acc) rescale while
    // the tile max stays within THR=8 of the running max (P bounded by 2^8).
    float mx = fmaxf(fmaxf(fmaxf(sc[0][0], sc[0][1]), fmaxf(sc[0][2], sc[0][3])),
                     fmaxf(fmaxf(sc[1][0], sc[1][1]), fmaxf(sc[1][2], sc[1][3])));
    mx = fmaxf(mx, __shfl_xor(mx, 16, 64));
    mx = fmaxf(mx, __shfl_xor(mx, 32, 64));
    if (__any(mx > mrun + 8.f)) {  // wave-uniform rescale
      const float mnew = fmaxf(mrun, mx);
      const float alpha = exp2f(mrun - mnew);
      mrun = mnew;
      lrun *= alpha;
#pragma unroll
      for (int d = 0; d < 8; ++d)
#pragma unroll
        for (int r = 0; r < 4; ++r) acc[d][r] *= alpha;
    }
    float p[2][4];
    float sm = 0.f;
#pragma unroll
    for (int g = 0; g < 2; ++g)
#pragma unroll
      for (int r = 0; r < 4; ++r) { p[g][r] = exp2f(sc[g][r] - mrun); sm += p[g][r]; }
    sm += __shfl_xor(sm, 16, 64);
    sm += __shfl_xor(sm, 32, 64);
    lrun += sm;

    // quad-exchange P (S^T C-layout) -> PV B-frag P[n=qrow l16][k=key quad*8+j].
    // dest (quad,j): src lane 32*(quad&1)+l16 (+16 for j>=4), frag g=quad>>1, reg j&3.
    u32 pk[2][2];
#pragma unroll
    for (int g = 0; g < 2; ++g) {
      pk[g][0] = (u32)f2bf(p[g][0]) | ((u32)f2bf(p[g][1]) << 16);
      pk[g][1] = (u32)f2bf(p[g][2]) | ((u32)f2bf(p[g][3]) << 16);
    }
    const int la = ((quad & 1) << 5) + l16;
    const int lb = la + 16;
    const u32 a0 = (u32)__shfl((int)pk[0][0], la, 64);
    const u32 a1 = (u32)__shfl((int)pk[0][1], la, 64);
    const u32 a2 = (u32)__shfl((int)pk[0][0], lb, 64);
    const u32 a3 = (u32)__shfl((int)pk[0][1], lb, 64);
    const u32 b0 = (u32)__shfl((int)pk[1][0], la, 64);
    const u32 b1 = (u32)__shfl((int)pk[1][1], la, 64);
    const u32 b2 = (u32)__shfl((int)pk[1][0], lb, 64);
    const u32 b3 = (u32)__shfl((int)pk[1][1], lb, 64);
    const bool hi = quad >= 2;
    const u32x4 pw = {hi ? b0 : a0, hi ? b1 : a1, hi ? b2 : a2, hi ? b3 : a3};
    const s16x8 pf = __builtin_bit_cast(s16x8, pw);

    // PV: out^T += V^T * P  (A = V^T[m=dim][k=key], B = P[n=qrow][k=key])
    __builtin_amdgcn_s_setprio(1);
#pragma unroll
    for (int dd = 0; dd < 8; ++dd) {
      const s16x8 vf = *(const s16x8*)(
          &Vsc[(dd * 16 + l16) * 32 + ((quad ^ ((l16 >> 1) & 3)) << 3)]);
      acc[dd] = __builtin_amdgcn_mfma_f32_16x16x32_bf16(vf, pf, acc[dd], 0, 0, 0);
    }
    __builtin_amdgcn_s_setprio(0);
    bt = bt == 2 ? 0 : bt + 1;
  }

  // epilogue: lane l16 owns q-row qbase+l16; dims dd*16+quad*4+r -> ushort4 stores
  const int b = bh >> 4, h = bh & 15;
  u16* op = out + ((long)b * 2048 + qbase + l16) * 2048 + h * 128;
  const float inv_l = 1.0f / lrun;
#pragma unroll
  for (int dd = 0; dd < 8; ++dd) {
    ushort4 o4;
    o4.x = f2bf(acc[dd][0] * inv_l);
    o4.y = f2bf(acc[dd][1] * inv_l);
    o4.z = f2bf(acc[dd][2] * inv_l);
    o4.w = f2bf(acc[dd][3] * inv_l);
    *(ushort4*)(op + dd * 16 + quad * 4) = o4;
  }
}

extern "C" void kernel_launch(void* const* d_in, const int* in_sizes, int n_in,
                              void* d_out, int out_size, void* d_ws, size_t ws_size,
                              hipStream_t stream) {
  const float* hidden = (const float*)d_in[0];  // [2,2048,2048]
  const float* w_qkv = (const float*)d_in[1];   // [6144,2048]
  const float* w_out = (const float*)d_in[2];   // [2048,2048]
  float* out = (float*)d_out;                   // [2,2048,2048] fp32
  char* ws = (char*)d_ws;

  // workspace layout (112 MB total, all 16B aligned)
  u16* hid_b  = (u16*)(ws + (size_t)0);          // hidden bf16
  u16* wqkv_b = (u16*)(ws + (size_t)16777216);   // w_qkv bf16
  u16* wout_b = (u16*)(ws + (size_t)41943040);   // w_out bf16
  u16* qb     = (u16*)(ws + (size_t)50331648);   // q (unroped) [B,H,S,D]
  u16* kb     = (u16*)(ws + (size_t)67108864);   // k (roped)   [B,H,S,D]
  u16* vb     = (u16*)(ws + (size_t)83886080);   // v^T [B,H,D,S]
  u16* ao     = (u16*)(ws + (size_t)100663296);  // attn out [B,S,E]

  cast3_kernel<<<24576, 256, 0, stream>>>(hidden, hid_b, 2097152,
                                          w_qkv, wqkv_b, 3145728,
                                          w_out, wout_b, 1048576);

  // qkv projection, 128^2 R4 GEMM (reverted: proven 136.5us; 256^2 port pinned at
  // ~147 across two fix attempts) with fused split/transpose/k-rope epilogue
  gemm_bt_kernel<1><<<dim3(48, 32), 256, 0, stream>>>(hid_b, wqkv_b, 2048, 6144,
                                                      nullptr, qb, kb, vb);
  // causal flash attention (q-rope + scale in prologue), 3-deep staging ring
  attn_kernel<<<1024, 256, 0, stream>>>(qb, kb, vb, ao);
  // output projection -> fp32
  gemm_bt_kernel<0><<<dim3(16, 32), 256, 0, stream>>>(ao, wout_b, 2048, 2048,
                                                      out, nullptr, nullptr, nullptr);
}

// Round 4
// 373.905 us; speedup vs baseline: 1.0747x; 1.0266x over previous
//
#include <hip/hip_runtime.h>

typedef unsigned short u16;
typedef unsigned int u32;
typedef __attribute__((ext_vector_type(4))) float f32x4;
typedef __attribute__((ext_vector_type(8))) short s16x8;
typedef __attribute__((ext_vector_type(4))) unsigned int u32x4;

#define DEVI static __device__ __forceinline__

// B=2, S=2048, E=2048, H=16, D=128, MP=4, local=512; qkv cols: [q(512) v(512) k(512)] x4
// k-rope fused into QKV-GEMM epilogue; q-rope (+ (1/sqrt(128))*log2(e) scale) fused into
// attention prologue; softmax in exp2 domain.

#define ROPE_C (-13.287712379549449f / 32.0f)  // -log2(10000)/32
#define QSCALE 0.12751743f                     // log2(e)/sqrt(128)

DEVI u16 f2bf(float f) {
  u32 u = __float_as_uint(f);
  return (u16)((u + 0x7FFFu + ((u >> 16) & 1u)) >> 16);  // round-to-nearest-even
}
DEVI float bf2f(u16 h) { return __uint_as_float(((u32)h) << 16); }

DEVI void async_copy16(const u16* g, u16* l) {
  // dest = wave-uniform LDS base + lane*16 (gfx950 global_load_lds_dwordx4)
  __builtin_amdgcn_global_load_lds((__attribute__((address_space(1))) void*)g,
                                   (__attribute__((address_space(3))) void*)l, 16, 0, 0);
}

// fused fp32->bf16 cast of all three inputs
__global__ __launch_bounds__(256) void cast3_kernel(
    const float* __restrict__ s0, u16* __restrict__ d0, int n0,
    const float* __restrict__ s1, u16* __restrict__ d1, int n1,
    const float* __restrict__ s2, u16* __restrict__ d2, int n2) {
  int i = blockIdx.x * 256 + threadIdx.x;
  const float* s;
  u16* d;
  if (i < n0) {
    s = s0; d = d0;
  } else if (i < n0 + n1) {
    s = s1; d = d1; i -= n0;
  } else if (i < n0 + n1 + n2) {
    s = s2; d = d2; i -= n0 + n1;
  } else {
    return;
  }
  const float4 v = ((const float4*)s)[i];
  ushort4 o;
  o.x = f2bf(v.x); o.y = f2bf(v.y); o.z = f2bf(v.z); o.w = f2bf(v.w);
  ((ushort4*)d)[i] = o;
}

// C[m,n] = sum_k A[m,k]*B[n,k]; A,B row-major bf16, K contiguous (B^T GEMM).
// 128x128 tile, BK=32, 4 waves 2x2 of 64x64, 16x16x32 MFMA, 4x4 frags/wave.
// R4 structure (best measured, 136.5us QKV): A,B staged through 3-deep LDS via
// global_load_lds w16, XOR-swizzled, vmcnt(4) + raw s_barrier in steady state,
// 3 blocks/CU (cross-block overlap hides the barrier drains). Inline epilogue.
// EPI=0: C fp32 store. EPI=1: scatter qkv -> q[B,H,S,D], k(roped)[B,H,S,D], v^T[B,H,D,S].
template <int EPI>
__global__ __launch_bounds__(256, 3) void gemm_bt_kernel(
    const u16* __restrict__ A, const u16* __restrict__ Bm, int K, int N,
    float* __restrict__ C, u16* __restrict__ qo, u16* __restrict__ ko, u16* __restrict__ vo) {
  __shared__ __attribute__((aligned(16))) u16 As[3][128 * 32];  // 8KB each
  __shared__ __attribute__((aligned(16))) u16 Bs[3][128 * 32];  // 8KB each
  const int tid = threadIdx.x;
  const int w = tid >> 6, lane = tid & 63;
  const int quad = lane >> 4, l16 = lane & 15;
  const int wrow = (w >> 1) * 64, wcol = (w & 1) * 64;
  const long tileM = (long)blockIdx.y * 128;
  const long tileN = (long)blockIdx.x * 128;

  f32x4 acc[4][4];
#pragma unroll
  for (int i = 0; i < 4; ++i)
#pragma unroll
    for (int j = 0; j < 4; ++j) acc[i][j] = f32x4{0.f, 0.f, 0.f, 0.f};

  // staging: wave w covers tile rows [w*32, w*32+32) in two 16-row chunks.
  const u16* aptr[2];
  const u16* bptr[2];
  int ldso[2];
#pragma unroll
  for (int c = 0; c < 2; ++c) {
    const int r0 = (w * 2 + c) * 16;
    const int row = r0 + (lane >> 2);
    const int colsw = (((lane & 3) ^ ((row >> 1) & 3)) << 3);
    aptr[c] = A + (tileM + row) * (long)K + colsw;
    bptr[c] = Bm + (tileN + row) * (long)K + colsw;
    ldso[c] = r0 * 32;
  }

  auto stage = [&](int k0, int buf) {
#pragma unroll
    for (int c = 0; c < 2; ++c) {
      async_copy16(aptr[c] + k0, &As[buf][ldso[c]]);
      async_copy16(bptr[c] + k0, &Bs[buf][ldso[c]]);
    }
  };

  stage(0, 0);
  stage(32, 1);

  const int psw = (quad ^ ((l16 >> 1) & 3)) << 3;  // read-side swizzle (lane-constant)

  int bt = 0;
  for (int k0 = 0; k0 < K; k0 += 32) {
    if (k0 + 32 < K)
      __builtin_amdgcn_s_waitcnt(0x0f74);  // vmcnt(4): tile t landed, t+1 in flight
    else
      __builtin_amdgcn_s_waitcnt(0x0f70);  // last tile: vmcnt(0)
    __builtin_amdgcn_s_barrier();          // raw barrier: no compiler-forced drain
    if (k0 + 64 < K) stage(k0 + 64, bt == 0 ? 2 : bt - 1);

    s16x8 af[4], bfr[4];
#pragma unroll
    for (int i = 0; i < 4; ++i)
      af[i] = *(const s16x8*)(&As[bt][(wrow + i * 16 + l16) * 32 + psw]);
#pragma unroll
    for (int j = 0; j < 4; ++j)
      bfr[j] = *(const s16x8*)(&Bs[bt][(wcol + j * 16 + l16) * 32 + psw]);
#pragma unroll
    for (int i = 0; i < 4; ++i)
#pragma unroll
      for (int j = 0; j < 4; ++j)
        acc[i][j] = __builtin_amdgcn_mfma_f32_16x16x32_bf16(af[i], bfr[j], acc[i][j], 0, 0, 0);
    bt = bt == 2 ? 0 : bt + 1;
  }

  // ---- inline epilogue (single call site; acc stays in registers) ----
  const int b = (int)(tileM >> 11);  // 128-row tile never straddles batch
#pragma unroll
  for (int i = 0; i < 4; ++i) {
#pragma unroll
    for (int j = 0; j < 4; ++j) {
      const int rowb = (int)((tileM + wrow + i * 16 + quad * 4) & 2047);  // s of reg 0
      if (EPI == 0) {
#pragma unroll
        for (int r = 0; r < 4; ++r) {
          const long row = tileM + wrow + i * 16 + quad * 4 + r;
          C[row * N + tileN + wcol + j * 16 + l16] = acc[i][j][r];
        }
      } else {
        const long col0 = tileN + wcol + j * 16;  // wave-uniform base col of this frag
        const int mp = (int)(col0 / 1536);
        const int cc0 = (int)(col0 - (long)mp * 1536);
        const int part = cc0 >> 9;     // 0:q 1:v 2:k (uniform per frag)
        const int idx0 = cc0 & 511;
        const int head = mp * 4 + (idx0 >> 7);
        const int dim0 = idx0 & 127;
        const int dim = dim0 + l16;
        const long bh = (long)(b * 16 + head);
        if (part == 1) {
#pragma unroll
          for (int r = 0; r < 4; ++r)
            vo[(bh * 128 + dim) * 2048 + rowb + r] = f2bf(acc[i][j][r]);  // v^T
        } else {
          float y[4];
          if (part == 2 && dim0 < 64) {
            // k-rope: pair partner is adjacent lane (col parity == l16 parity)
            const int jj = dim >> 1;
            const float inv = exp2f((float)jj * ROPE_C);
#pragma unroll
            for (int r = 0; r < 4; ++r) {
              const float v = acc[i][j][r];
              const float pv = __shfl_xor(v, 1, 64);
              const float ang = (float)(rowb + r) * inv;
              const float sn = __sinf(ang), cs = __cosf(ang);
              y[r] = (l16 & 1) ? (v * cs + pv * sn) : (v * cs - pv * sn);
            }
          } else {
#pragma unroll
            for (int r = 0; r < 4; ++r) y[r] = acc[i][j][r];
          }
          u16* dst = (part == 0) ? qo : ko;
#pragma unroll
          for (int r = 0; r < 4; ++r)
            dst[(bh * 2048 + rowb + r) * 128 + dim] = f2bf(y[r]);
        }
      }
    }
  }
}

// Flash attention v4.3: swapped-operand design. Block = 64 q rows (4 waves x 16 rows),
// 32-key tiles, 3-deep LDS ring + counted vmcnt(4) (4 DMAs/wave/tile).
// S^T = K*Q^T (A=K, B=Q): each lane holds 8 scores of ONE q-row -> softmax reduce =
// in-lane + 2 shfl; m/l scalars per lane.
// R4 change (zero-shuffle P): K is staged in a PERMUTED row order -- global key
// u*8 + g*4 + r is stored at LDS row g*16 + u*4 + r (bijective bit-shuffle, applied
// on the per-lane global source address; LDS dest stays linear for global_load_lds).
// Then the S^T C-layout reg (g,r) at lane-quad u holds exactly key u*8+g*4+r, which
// IS the PV B-frag layout: pf = in-lane pack {pk[0][0],pk[0][1],pk[1][0],pk[1][1]}.
// This deletes the 8-shfl quad-exchange + hi/lo selects (8 ds_bpermute per tile per
// wave) from the LDS-bound inner loop. Only other change: causal-mask key id is now
// k0 + quad*8 + g*4 + r. Softmax sum order over keys changes (sub-ulp reorder).
// Keeps: setprio around MFMA clusters (T5), defer-max THR=8 (T13), QK^T g-interleave,
// raw s_barrier after explicit vmcnt. PV = V^T*P gives out^T; ushort4 stores.
__global__ __launch_bounds__(256, 3) void attn_kernel(
    const u16* __restrict__ q, const u16* __restrict__ k,
    const u16* __restrict__ vT, u16* __restrict__ out) {
  __shared__ __attribute__((aligned(16))) u16 Ks[3][32 * 128];  // 8KB each
  __shared__ __attribute__((aligned(16))) u16 Vs[3][128 * 32];  // 8KB each
  const int tid = threadIdx.x;
  const int w = tid >> 6, lane = tid & 63;
  const int quad = lane >> 4, l16 = lane & 15;
  const int qt = 31 - (blockIdx.x >> 5);  // heavy tiles dispatched first
  const int bh = blockIdx.x & 31;
  const int qbase = qt * 64 + w * 16;

  const u16* qp = q + ((long)bh * 2048 + qbase) * 128;
  const u16* kp = k + (long)bh * 2048 * 128;
  const u16* vp = vT + (long)bh * 128 * 2048;

  // Q B-frag: Q[n=l16][kdim = c*32 + quad*8 + j], roped + scaled in fp32
  const float spos = (float)(qbase + l16);
  s16x8 qf[4];
#pragma unroll
  for (int c = 0; c < 4; ++c) {
    const s16x8 raw = *(const s16x8*)(qp + l16 * 128 + c * 32 + quad * 8);
    s16x8 ov;
    if (c < 2) {  // dims < 64: rotate pairs (in-lane: 2m, 2m+1)
#pragma unroll
      for (int m = 0; m < 4; ++m) {
        const int jj = c * 16 + quad * 4 + m;
        const float inv = exp2f((float)jj * ROPE_C);
        const float ang = spos * inv;
        const float sn = __sinf(ang), cs = __cosf(ang);
        const float x0 = bf2f((u16)raw[2 * m]), x1 = bf2f((u16)raw[2 * m + 1]);
        ov[2 * m] = (short)f2bf((x0 * cs - x1 * sn) * QSCALE);
        ov[2 * m + 1] = (short)f2bf((x1 * cs + x0 * sn) * QSCALE);
      }
    } else {      // dims >= 64: pass-through, scale only
#pragma unroll
      for (int e = 0; e < 8; ++e) ov[e] = (short)f2bf(bf2f((u16)raw[e]) * QSCALE);
    }
    qf[c] = ov;
  }

  f32x4 acc[8];  // out^T: acc[dd] rows = dims dd*16+quad*4+r, col = q-row l16
#pragma unroll
  for (int d = 0; d < 8; ++d) acc[d] = f32x4{0.f, 0.f, 0.f, 0.f};
  float mrun = -1e30f, lrun = 0.f;  // per-lane scalars (q-row = qbase+l16)

  // stage one 32-key tile: wave w stages LDS K-rows [w*8,w*8+8) and V dims
  // [w*32,w*32+32); exactly 4 async DMAs per wave per tile (vmcnt is per-wave).
  // K rows are PERMUTED: LDS row rr holds global key s(rr) = ((rr>>2)&3)*8 +
  // ((rr>>4)&1)*4 + (rr&3)  (bijection; see kernel comment).
  auto stage = [&](int k0, int buf) {
    const int ko = lane >> 4, cl = lane & 15;
#pragma unroll
    for (int i = 0; i < 2; ++i) {
      const int keyt = w * 8 + i * 4;
      const int rr = keyt + ko;  // LDS row this lane fills
      const int sk = ((rr >> 2) & 3) * 8 + ((rr >> 4) & 1) * 4 + (rr & 3);
      async_copy16(kp + (long)(k0 + sk) * 128 + ((cl ^ (rr & 15)) << 3),
                   &Ks[buf][keyt * 128]);
    }
    const int ld = lane >> 2, c4 = lane & 3;
#pragma unroll
    for (int i = 0; i < 2; ++i) {
      const int db = w * 32 + i * 16;
      const int d = db + ld;
      async_copy16(vp + (long)d * 2048 + k0 + ((c4 ^ ((d >> 1) & 3)) << 3),
                   &Vs[buf][db * 32]);
    }
  };

  const int nt = 2 * qt + 2;  // nt >= 2 always
  stage(0, 0);
  stage(32, 1);

  int bt = 0;
  for (int t = 0; t < nt; ++t) {
    const int k0 = t * 32;
    if (t + 1 < nt)
      __builtin_amdgcn_s_waitcnt(0x0f74);  // vmcnt(4): tile t landed, t+1 in flight
    else
      __builtin_amdgcn_s_waitcnt(0x0f70);  // last tile: vmcnt(0)
    __builtin_amdgcn_s_barrier();          // all waves' tile-t DMA done; buf t-1 free
    if (t + 2 < nt) stage(k0 + 64, bt == 0 ? 2 : bt - 1);
    const u16* Ksc = Ks[bt];
    const u16* Vsc = Vs[bt];

    // S^T = K*Q^T: sc[g] reg r at lane-quad u holds key k0 + u*8 + g*4 + r (permuted
    // staging), col = q-row l16. g interleaved inside c: consecutive MFMAs independent.
    f32x4 sc[2];
    sc[0] = f32x4{0.f, 0.f, 0.f, 0.f};
    sc[1] = f32x4{0.f, 0.f, 0.f, 0.f};
    __builtin_amdgcn_s_setprio(1);
#pragma unroll
    for (int c = 0; c < 4; ++c) {
      const s16x8 kf0 = *(const s16x8*)(
          &Ksc[(0 * 16 + l16) * 128 + ((((c << 2) + quad) ^ l16) << 3)]);
      const s16x8 kf1 = *(const s16x8*)(
          &Ksc[(1 * 16 + l16) * 128 + ((((c << 2) + quad) ^ l16) << 3)]);
      sc[0] = __builtin_amdgcn_mfma_f32_16x16x32_bf16(kf0, qf[c], sc[0], 0, 0, 0);
      sc[1] = __builtin_amdgcn_mfma_f32_16x16x32_bf16(kf1, qf[c], sc[1], 0, 0, 0);
    }
    __builtin_amdgcn_s_setprio(0);
    if (k0 + 31 > qbase) {  // tile may cross the diagonal (wave-uniform branch)
      const int qrow = qbase + l16;
#pragma unroll
      for (int g = 0; g < 2; ++g) {
        const int keyb = k0 + quad * 8 + g * 4;  // permuted key id of reg 0
#pragma unroll
        for (int r = 0; r < 4; ++r)
          if (keyb + r > qrow) sc[g][r] = -1e30f;
      }
    }
    // online softmax (exp2 domain), defer-max (T13): skip the O(acc) rescale while
    // the tile max stays within THR=8 of the running max (P bounded by 2^8).
    float mx = fmaxf(fmaxf(fmaxf(sc[0][0], sc[0][1]), fmaxf(sc[0][2], sc[0][3])),
                     fmaxf(fmaxf(sc[1][0], sc[1][1]), fmaxf(sc[1][2], sc[1][3])));
    mx = fmaxf(mx, __shfl_xor(mx, 16, 64));
    mx = fmaxf(mx, __shfl_xor(mx, 32, 64));
    if (__any(mx > mrun + 8.f)) {  // wave-uniform rescale
      const float mnew = fmaxf(mrun, mx);
      const float alpha = exp2f(mrun - mnew);
      mrun = mnew;
      lrun *= alpha;
#pragma unroll
      for (int d = 0; d < 8; ++d)
#pragma unroll
        for (int r = 0; r < 4; ++r) acc[d][r] *= alpha;
    }
    float p[2][4];
    float sm = 0.f;
#pragma unroll
    for (int g = 0; g < 2; ++g)
#pragma unroll
      for (int r = 0; r < 4; ++r) { p[g][r] = exp2f(sc[g][r] - mrun); sm += p[g][r]; }
    sm += __shfl_xor(sm, 16, 64);
    sm += __shfl_xor(sm, 32, 64);
    lrun += sm;

    // P -> PV B-frag, fully in-lane (permuted staging made C-layout == B-frag layout):
    // pf element j needs key quad*8 + j; reg (g,r) holds key quad*8 + g*4 + r -> j = g*4+r.
    u32 pk[2][2];
#pragma unroll
    for (int g = 0; g < 2; ++g) {
      pk[g][0] = (u32)f2bf(p[g][0]) | ((u32)f2bf(p[g][1]) << 16);
      pk[g][1] = (u32)f2bf(p[g][2]) | ((u32)f2bf(p[g][3]) << 16);
    }
    const u32x4 pw = {pk[0][0], pk[0][1], pk[1][0], pk[1][1]};
    const s16x8 pf = __builtin_bit_cast(s16x8, pw);

    // PV: out^T += V^T * P  (A = V^T[m=dim][k=key], B = P[n=qrow][k=key])
    __builtin_amdgcn_s_setprio(1);
#pragma unroll
    for (int dd = 0; dd < 8; ++dd) {
      const s16x8 vf = *(const s16x8*)(
          &Vsc[(dd * 16 + l16) * 32 + ((quad ^ ((l16 >> 1) & 3)) << 3)]);
      acc[dd] = __builtin_amdgcn_mfma_f32_16x16x32_bf16(vf, pf, acc[dd], 0, 0, 0);
    }
    __builtin_amdgcn_s_setprio(0);
    bt = bt == 2 ? 0 : bt + 1;
  }

  // epilogue: lane l16 owns q-row qbase+l16; dims dd*16+quad*4+r -> ushort4 stores
  const int b = bh >> 4, h = bh & 15;
  u16* op = out + ((long)b * 2048 + qbase + l16) * 2048 + h * 128;
  const float inv_l = 1.0f / lrun;
#pragma unroll
  for (int dd = 0; dd < 8; ++dd) {
    ushort4 o4;
    o4.x = f2bf(acc[dd][0] * inv_l);
    o4.y = f2bf(acc[dd][1] * inv_l);
    o4.z = f2bf(acc[dd][2] * inv_l);
    o4.w = f2bf(acc[dd][3] * inv_l);
    *(ushort4*)(op + dd * 16 + quad * 4) = o4;
  }
}

extern "C" void kernel_launch(void* const* d_in, const int* in_sizes, int n_in,
                              void* d_out, int out_size, void* d_ws, size_t ws_size,
                              hipStream_t stream) {
  const float* hidden = (const float*)d_in[0];  // [2,2048,2048]
  const float* w_qkv = (const float*)d_in[1];   // [6144,2048]
  const float* w_out = (const float*)d_in[2];   // [2048,2048]
  float* out = (float*)d_out;                   // [2,2048,2048] fp32
  char* ws = (char*)d_ws;

  // workspace layout (112 MB total, all 16B aligned)
  u16* hid_b  = (u16*)(ws + (size_t)0);          // hidden bf16
  u16* wqkv_b = (u16*)(ws + (size_t)16777216);   // w_qkv bf16
  u16* wout_b = (u16*)(ws + (size_t)41943040);   // w_out bf16
  u16* qb     = (u16*)(ws + (size_t)50331648);   // q (unroped) [B,H,S,D]
  u16* kb     = (u16*)(ws + (size_t)67108864);   // k (roped)   [B,H,S,D]
  u16* vb     = (u16*)(ws + (size_t)83886080);   // v^T [B,H,D,S]
  u16* ao     = (u16*)(ws + (size_t)100663296);  // attn out [B,S,E]

  cast3_kernel<<<24576, 256, 0, stream>>>(hidden, hid_b, 2097152,
                                          w_qkv, wqkv_b, 3145728,
                                          w_out, wout_b, 1048576);

  // qkv projection, 128^2 R4 GEMM with fused split/transpose/k-rope epilogue
  gemm_bt_kernel<1><<<dim3(48, 32), 256, 0, stream>>>(hid_b, wqkv_b, 2048, 6144,
                                                      nullptr, qb, kb, vb);
  // causal flash attention (q-rope + scale in prologue), zero-shuffle P path
  attn_kernel<<<1024, 256, 0, stream>>>(qb, kb, vb, ao);
  // output projection -> fp32
  gemm_bt_kernel<0><<<dim3(16, 32), 256, 0, stream>>>(ao, wout_b, 2048, 2048,
                                                      out, nullptr, nullptr, nullptr);
}